// Round 1
// baseline (540.796 us; speedup 1.0000x reference)
//
#include <hip/hip_runtime.h>

#define D   128
#define NB  16    // nodes per block (node kernels)
#define TPB 128   // threads per block (node kernels)

__device__ __forceinline__ float sigmoidf(float v) {
    return 1.0f / (1.0f + __expf(-v));
}

// ---------------------------------------------------------------------------
// Kernel 1: per-node edge-MLP precompute.
//   P0(n) = relu(h[n] @ W1e[:D]  + b1e) @ W2e + b2e ; g0 = sigmoid(P0·Wg+bg)
//   P1(n) = relu(h[n] @ W1e[D:]  + b1e) @ W2e + b2e ; g1 = sigmoid(P1·Wg+bg)
//   R0 = P0*g0, Q1 = P1*g1
// ---------------------------------------------------------------------------
__global__ __launch_bounds__(TPB) void node_pre_kernel(
    const float* __restrict__ h,
    const float* __restrict__ W1e, const float* __restrict__ b1e,
    const float* __restrict__ W2e, const float* __restrict__ b2e,
    const float* __restrict__ Wg,  const float* __restrict__ bg,
    float* __restrict__ R0, float* __restrict__ Q1, int N)
{
    __shared__ float h_s[NB][D];
    __shared__ float t_s[NB][D];
    __shared__ float red_s[2][NB];

    const int j    = threadIdx.x;      // output channel
    const int wave = j >> 6;
    const int lane = j & 63;
    const int base = blockIdx.x * NB;
    const int nlim = (N - base < NB) ? (N - base) : NB;

    for (int idx = j; idx < NB * D; idx += TPB) {
        int n = idx >> 7, k = idx & 127;
        int node = base + n; if (node >= N) node = N - 1;
        h_s[n][k] = h[(size_t)node * D + k];
    }
    __syncthreads();

    const float b1  = b1e[j];
    const float b2  = b2e[j];
    const float wg  = Wg[j];
    const float bgv = bg[0];

    for (int half = 0; half < 2; ++half) {
        const float* __restrict__ W1 = W1e + (size_t)half * D * D;

        // layer 1: t = relu(h @ W1 + b1)
        float acc[NB];
        #pragma unroll
        for (int n = 0; n < NB; ++n) acc[n] = 0.f;
        for (int k4 = 0; k4 < D; k4 += 4) {
            const float w0 = W1[(k4 + 0) * D + j];
            const float w1 = W1[(k4 + 1) * D + j];
            const float w2 = W1[(k4 + 2) * D + j];
            const float w3 = W1[(k4 + 3) * D + j];
            #pragma unroll
            for (int n = 0; n < NB; ++n) {
                const float4 hv = *reinterpret_cast<const float4*>(&h_s[n][k4]);
                acc[n] += w0 * hv.x + w1 * hv.y + w2 * hv.z + w3 * hv.w;
            }
        }
        __syncthreads();   // previous-iteration t_s / red_s readers are done
        #pragma unroll
        for (int n = 0; n < NB; ++n) t_s[n][j] = fmaxf(acc[n] + b1, 0.f);
        __syncthreads();

        // layer 2: p = t @ W2e + b2
        float p[NB];
        #pragma unroll
        for (int n = 0; n < NB; ++n) p[n] = 0.f;
        for (int k4 = 0; k4 < D; k4 += 4) {
            const float w0 = W2e[(k4 + 0) * D + j];
            const float w1 = W2e[(k4 + 1) * D + j];
            const float w2 = W2e[(k4 + 2) * D + j];
            const float w3 = W2e[(k4 + 3) * D + j];
            #pragma unroll
            for (int n = 0; n < NB; ++n) {
                const float4 tv = *reinterpret_cast<const float4*>(&t_s[n][k4]);
                p[n] += w0 * tv.x + w1 * tv.y + w2 * tv.z + w3 * tv.w;
            }
        }
        #pragma unroll
        for (int n = 0; n < NB; ++n) p[n] += b2;

        // gate: g = sigmoid(p · Wg + bg), reduce over the 128 channels
        #pragma unroll
        for (int n = 0; n < NB; ++n) {
            float v = p[n] * wg;
            #pragma unroll
            for (int off = 32; off > 0; off >>= 1) v += __shfl_down(v, off, 64);
            if (lane == 0) red_s[wave][n] = v;
        }
        __syncthreads();

        float* __restrict__ outp = (half == 0) ? R0 : Q1;
        #pragma unroll
        for (int n = 0; n < NB; ++n) {
            if (n < nlim) {
                const float g = sigmoidf(red_s[0][n] + red_s[1][n] + bgv);
                outp[(size_t)(base + n) * D + j] = p[n] * g;
            }
        }
    }
}

// ---------------------------------------------------------------------------
// Kernel 2: edge scatter.  mi1[dst] += Q1[src];  cnt[dst] += 1.
// One wave (64 lanes) per edge; 2 floats per lane.
// ---------------------------------------------------------------------------
__global__ __launch_bounds__(256) void edge_scatter_kernel(
    const int* __restrict__ ei, int E,
    const float* __restrict__ Q1,
    float* __restrict__ mi1,
    int* __restrict__ cnt)
{
    const int e = blockIdx.x * 4 + (threadIdx.x >> 6);
    if (e >= E) return;
    const int lane = threadIdx.x & 63;
    const int s = ei[e];        // src = edge_index[0]
    const int d = ei[E + e];    // dst = edge_index[1]
    if (lane == 0) atomicAdd(&cnt[d], 1);
    const float2 q = *reinterpret_cast<const float2*>(&Q1[(size_t)s * D + lane * 2]);
    atomicAdd(&mi1[(size_t)d * D + lane * 2 + 0], q.x);
    atomicAdd(&mi1[(size_t)d * D + lane * 2 + 1], q.y);
}

// ---------------------------------------------------------------------------
// Kernel 3: node MLP + residual + output (x passthrough fused).
//   row0 in: cnt*R0, row1 in: mi1, row2 in: h.  rows 0,1 use W1n[:D], row2 W1n[D:].
//   out[n,r,:] = h[n] + relu(in_r @ W1x + b1n) @ W2n + b2n
// ---------------------------------------------------------------------------
__global__ __launch_bounds__(TPB) void node_mlp_kernel(
    const float* __restrict__ h,  const float* __restrict__ x,
    const float* __restrict__ R0, const float* __restrict__ mi1,
    const int* __restrict__ cnt,
    const float* __restrict__ W1n, const float* __restrict__ b1n,
    const float* __restrict__ W2n, const float* __restrict__ b2n,
    float* __restrict__ out_h, float* __restrict__ out_x, int N)
{
    __shared__ float in_s[3][NB][D];
    __shared__ float t_s[NB][D];

    const int j    = threadIdx.x;
    const int base = blockIdx.x * NB;
    const int nlim = (N - base < NB) ? (N - base) : NB;

    for (int idx = j; idx < NB * D; idx += TPB) {
        int n = idx >> 7, k = idx & 127;
        int node = base + n; if (node >= N) node = N - 1;
        const size_t g = (size_t)node * D + k;
        const float c = (float)cnt[node];
        in_s[0][n][k] = c * R0[g];
        in_s[1][n][k] = mi1[g];
        in_s[2][n][k] = h[g];
    }
    {   // x passthrough: 3 floats per node
        const int xi = blockIdx.x * (NB * 3) + j;
        if (j < NB * 3 && xi < N * 3) out_x[xi] = x[xi];
    }
    __syncthreads();

    const float b1 = b1n[j], b2 = b2n[j];

    for (int r = 0; r < 3; ++r) {
        const float* __restrict__ W1 = W1n + (size_t)((r == 2) ? D * D : 0);

        float acc[NB];
        #pragma unroll
        for (int n = 0; n < NB; ++n) acc[n] = 0.f;
        for (int k4 = 0; k4 < D; k4 += 4) {
            const float w0 = W1[(k4 + 0) * D + j];
            const float w1 = W1[(k4 + 1) * D + j];
            const float w2 = W1[(k4 + 2) * D + j];
            const float w3 = W1[(k4 + 3) * D + j];
            #pragma unroll
            for (int n = 0; n < NB; ++n) {
                const float4 hv = *reinterpret_cast<const float4*>(&in_s[r][n][k4]);
                acc[n] += w0 * hv.x + w1 * hv.y + w2 * hv.z + w3 * hv.w;
            }
        }
        __syncthreads();   // previous-iteration t_s readers done
        #pragma unroll
        for (int n = 0; n < NB; ++n) t_s[n][j] = fmaxf(acc[n] + b1, 0.f);
        __syncthreads();

        float o[NB];
        #pragma unroll
        for (int n = 0; n < NB; ++n) o[n] = 0.f;
        for (int k4 = 0; k4 < D; k4 += 4) {
            const float w0 = W2n[(k4 + 0) * D + j];
            const float w1 = W2n[(k4 + 1) * D + j];
            const float w2 = W2n[(k4 + 2) * D + j];
            const float w3 = W2n[(k4 + 3) * D + j];
            #pragma unroll
            for (int n = 0; n < NB; ++n) {
                const float4 tv = *reinterpret_cast<const float4*>(&t_s[n][k4]);
                o[n] += w0 * tv.x + w1 * tv.y + w2 * tv.z + w3 * tv.w;
            }
        }
        #pragma unroll
        for (int n = 0; n < NB; ++n) {
            if (n < nlim) {
                out_h[((size_t)(base + n) * 3 + r) * D + j] = o[n] + b2 + in_s[2][n][j];
            }
        }
    }
}

// ---------------------------------------------------------------------------
extern "C" void kernel_launch(void* const* d_in, const int* in_sizes, int n_in,
                              void* d_out, int out_size, void* d_ws, size_t ws_size,
                              hipStream_t stream)
{
    const float* h   = (const float*)d_in[0];
    const float* x   = (const float*)d_in[1];
    const int*   ei  = (const int*)d_in[2];
    const float* W1e = (const float*)d_in[3];
    const float* b1e = (const float*)d_in[4];
    const float* W2e = (const float*)d_in[5];
    const float* b2e = (const float*)d_in[6];
    const float* Wg  = (const float*)d_in[7];
    const float* bg  = (const float*)d_in[8];
    const float* W1n = (const float*)d_in[9];
    const float* b1n = (const float*)d_in[10];
    const float* W2n = (const float*)d_in[11];
    const float* b2n = (const float*)d_in[12];

    const int N = in_sizes[0] / D;   // h is [N,1,D]
    const int E = in_sizes[2] / 2;   // edge_index is [2,E]

    // workspace layout: R0 | Q1 | mi1 | cnt
    float* R0  = (float*)d_ws;
    float* Q1  = R0 + (size_t)N * D;
    float* mi1 = Q1 + (size_t)N * D;
    int*   cnt = (int*)(mi1 + (size_t)N * D);

    float* out_h = (float*)d_out;                       // [N,3,D]
    float* out_x = out_h + (size_t)N * 3 * D;           // [N,3]

    // zero mi1 + cnt (contiguous)
    hipMemsetAsync(mi1, 0, (size_t)N * D * sizeof(float) + (size_t)N * sizeof(int), stream);

    const int nblocks = (N + NB - 1) / NB;
    node_pre_kernel<<<nblocks, TPB, 0, stream>>>(h, W1e, b1e, W2e, b2e, Wg, bg, R0, Q1, N);
    edge_scatter_kernel<<<(E + 3) / 4, 256, 0, stream>>>(ei, E, Q1, mi1, cnt);
    node_mlp_kernel<<<nblocks, TPB, 0, stream>>>(h, x, R0, mi1, cnt, W1n, b1n, W2n, b2n,
                                                 out_h, out_x, N);
}

// Round 2
// 242.675 us; speedup vs baseline: 2.2285x; 2.2285x over previous
//
#include <hip/hip_runtime.h>

#define D   128
#define NB  16    // nodes per block (node kernels)
#define TPB 128   // threads per block (node kernels)
#define NPG 4     // nodes per node-group (= NB / 4)

__device__ __forceinline__ float sigmoidf(float v) {
    return 1.0f / (1.0f + __expf(-v));
}

// ---------------------------------------------------------------------------
// Kernel 1: per-node edge-MLP precompute (register-blocked 4ch x 4node).
//   P0(n) = relu(h[n] @ W1e[:D] + b1e) @ W2e + b2e ; R0 = P0*sigmoid(P0.Wg+bg)
//   P1(n) = relu(h[n] @ W1e[D:] + b1e) @ W2e + b2e ; Q1 = P1*sigmoid(P1.Wg+bg)
// Thread (cg, ng): channels j0=4*cg..+3, nodes ng*NPG..+NPG-1.
// ---------------------------------------------------------------------------
__global__ __launch_bounds__(TPB) void node_pre_kernel(
    const float* __restrict__ h,
    const float* __restrict__ W1e, const float* __restrict__ b1e,
    const float* __restrict__ W2e, const float* __restrict__ b2e,
    const float* __restrict__ Wg,  const float* __restrict__ bg,
    float* __restrict__ R0, float* __restrict__ Q1, int N)
{
    __shared__ float h_s[NB][D];
    __shared__ float t_s[NB][D];

    const int tid  = threadIdx.x;
    const int cg   = tid & 31;       // channel group
    const int ng   = tid >> 5;       // node group 0..3
    const int j0   = cg * 4;
    const int base = blockIdx.x * NB;

    for (int idx = tid; idx < NB * (D / 4); idx += TPB) {
        int n = idx >> 5, k = (idx & 31) << 2;
        int node = base + n; if (node >= N) node = N - 1;
        *reinterpret_cast<float4*>(&h_s[n][k]) =
            *reinterpret_cast<const float4*>(&h[(size_t)node * D + k]);
    }
    __syncthreads();

    const float4 b1v = *reinterpret_cast<const float4*>(&b1e[j0]);
    const float4 b2v = *reinterpret_cast<const float4*>(&b2e[j0]);
    const float4 wgv = *reinterpret_cast<const float4*>(&Wg[j0]);
    const float  bgv = bg[0];

    for (int hf = 0; hf < 2; ++hf) {
        const float* __restrict__ W1 = W1e + (size_t)hf * D * D;

        // layer 1: t = relu(h @ W1 + b1)
        float acc[NPG][4] = {};
        for (int k = 0; k < D; k += 4) {
            const float4 w0 = *reinterpret_cast<const float4*>(&W1[(k + 0) * D + j0]);
            const float4 w1 = *reinterpret_cast<const float4*>(&W1[(k + 1) * D + j0]);
            const float4 w2 = *reinterpret_cast<const float4*>(&W1[(k + 2) * D + j0]);
            const float4 w3 = *reinterpret_cast<const float4*>(&W1[(k + 3) * D + j0]);
            #pragma unroll
            for (int t = 0; t < NPG; ++t) {
                const float4 hv = *reinterpret_cast<const float4*>(&h_s[ng * NPG + t][k]);
                acc[t][0] += hv.x * w0.x + hv.y * w1.x + hv.z * w2.x + hv.w * w3.x;
                acc[t][1] += hv.x * w0.y + hv.y * w1.y + hv.z * w2.y + hv.w * w3.y;
                acc[t][2] += hv.x * w0.z + hv.y * w1.z + hv.z * w2.z + hv.w * w3.z;
                acc[t][3] += hv.x * w0.w + hv.y * w1.w + hv.z * w2.w + hv.w * w3.w;
            }
        }
        __syncthreads();   // previous t_s readers done
        #pragma unroll
        for (int t = 0; t < NPG; ++t) {
            float4 tv;
            tv.x = fmaxf(acc[t][0] + b1v.x, 0.f);
            tv.y = fmaxf(acc[t][1] + b1v.y, 0.f);
            tv.z = fmaxf(acc[t][2] + b1v.z, 0.f);
            tv.w = fmaxf(acc[t][3] + b1v.w, 0.f);
            *reinterpret_cast<float4*>(&t_s[ng * NPG + t][j0]) = tv;
        }
        __syncthreads();

        // layer 2: p = t @ W2e + b2
        float p[NPG][4] = {};
        for (int k = 0; k < D; k += 4) {
            const float4 w0 = *reinterpret_cast<const float4*>(&W2e[(k + 0) * D + j0]);
            const float4 w1 = *reinterpret_cast<const float4*>(&W2e[(k + 1) * D + j0]);
            const float4 w2 = *reinterpret_cast<const float4*>(&W2e[(k + 2) * D + j0]);
            const float4 w3 = *reinterpret_cast<const float4*>(&W2e[(k + 3) * D + j0]);
            #pragma unroll
            for (int t = 0; t < NPG; ++t) {
                const float4 tv = *reinterpret_cast<const float4*>(&t_s[ng * NPG + t][k]);
                p[t][0] += tv.x * w0.x + tv.y * w1.x + tv.z * w2.x + tv.w * w3.x;
                p[t][1] += tv.x * w0.y + tv.y * w1.y + tv.z * w2.y + tv.w * w3.y;
                p[t][2] += tv.x * w0.z + tv.y * w1.z + tv.z * w2.z + tv.w * w3.z;
                p[t][3] += tv.x * w0.w + tv.y * w1.w + tv.z * w2.w + tv.w * w3.w;
            }
        }

        // gate + store: g = sigmoid(sum_j p_j * Wg_j + bg); out = p * g
        float* __restrict__ outp = (hf == 0) ? R0 : Q1;
        #pragma unroll
        for (int t = 0; t < NPG; ++t) {
            const float p0 = p[t][0] + b2v.x;
            const float p1 = p[t][1] + b2v.y;
            const float p2 = p[t][2] + b2v.z;
            const float p3 = p[t][3] + b2v.w;
            float s = p0 * wgv.x + p1 * wgv.y + p2 * wgv.z + p3 * wgv.w;
            #pragma unroll
            for (int m = 1; m <= 16; m <<= 1) s += __shfl_xor(s, m, 64);
            const float g = sigmoidf(s + bgv);
            const int node = base + ng * NPG + t;
            if (node < N) {
                const float4 ov = { p0 * g, p1 * g, p2 * g, p3 * g };
                *reinterpret_cast<float4*>(&outp[(size_t)node * D + j0]) = ov;
            }
        }
    }
}

// ---------------------------------------------------------------------------
// CSR build: histogram -> exclusive scan -> bucket fill (no fp atomics).
// ---------------------------------------------------------------------------
__global__ __launch_bounds__(256) void hist_kernel(
    const int* __restrict__ ei, int E, int* __restrict__ cnt)
{
    const int e = blockIdx.x * 256 + threadIdx.x;
    if (e < E) atomicAdd(&cnt[ei[E + e]], 1);
}

__global__ __launch_bounds__(1024) void scan_kernel(
    const int* __restrict__ cnt, int* __restrict__ off, int* __restrict__ cur, int N)
{
    __shared__ int wsum[16];
    __shared__ int carry_s;
    const int tid = threadIdx.x, lane = tid & 63, wid = tid >> 6;
    if (tid == 0) carry_s = 0;
    __syncthreads();
    for (int base = 0; base < N; base += 1024) {
        const int i = base + tid;
        const int orig = (i < N) ? cnt[i] : 0;
        int v = orig;
        #pragma unroll
        for (int o = 1; o < 64; o <<= 1) {
            int u = __shfl_up(v, o, 64);
            if (lane >= o) v += u;
        }
        if (lane == 63) wsum[wid] = v;
        __syncthreads();
        if (tid < 16) {
            int w = wsum[tid];
            #pragma unroll
            for (int o = 1; o < 16; o <<= 1) {
                int u = __shfl_up(w, o, 16);
                if (tid >= o) w += u;
            }
            wsum[tid] = w;
        }
        __syncthreads();
        const int add = carry_s + ((wid > 0) ? wsum[wid - 1] : 0);
        if (i < N) { const int ex = v - orig + add; off[i] = ex; cur[i] = ex; }
        __syncthreads();
        if (tid == 0) carry_s += wsum[15];
        __syncthreads();
    }
}

__global__ __launch_bounds__(256) void fill_kernel(
    const int* __restrict__ ei, int E, int* __restrict__ cur, int* __restrict__ bucket)
{
    const int e = blockIdx.x * 256 + threadIdx.x;
    if (e < E) {
        const int pos = atomicAdd(&cur[ei[E + e]], 1);
        bucket[pos] = ei[e];   // store src
    }
}

// ---------------------------------------------------------------------------
// Gather: mi1[n] = sum over edges with dst==n of Q1[src].
// One wave per node; 2 edges in flight (lane halves), float4 per lane.
// ---------------------------------------------------------------------------
__global__ __launch_bounds__(256) void gather_kernel(
    const int* __restrict__ bucket, const int* __restrict__ off,
    const int* __restrict__ cnt, const float* __restrict__ Q1,
    float* __restrict__ mi1, int N)
{
    const int n = blockIdx.x * 4 + (threadIdx.x >> 6);
    if (n >= N) return;
    const int lane = threadIdx.x & 63;
    const int hf   = lane >> 5;          // which edge of the pair
    const int c4   = (lane & 31) * 4;    // channel base
    const int beg  = off[n];
    const int deg  = cnt[n];
    float4 acc = { 0.f, 0.f, 0.f, 0.f };
    for (int i = hf; i < deg; i += 2) {
        const int s = bucket[beg + i];
        const float4 q = *reinterpret_cast<const float4*>(&Q1[(size_t)s * D + c4]);
        acc.x += q.x; acc.y += q.y; acc.z += q.z; acc.w += q.w;
    }
    acc.x += __shfl_xor(acc.x, 32, 64);
    acc.y += __shfl_xor(acc.y, 32, 64);
    acc.z += __shfl_xor(acc.z, 32, 64);
    acc.w += __shfl_xor(acc.w, 32, 64);
    if (hf == 0)
        *reinterpret_cast<float4*>(&mi1[(size_t)n * D + c4]) = acc;
}

// ---------------------------------------------------------------------------
// Kernel 3: node MLP + residual + output (register-blocked like node_pre).
//   row0 in: cnt*R0, row1 in: mi1, row2 in: h.  rows 0,1 use W1n[:D], row2 W1n[D:]
// ---------------------------------------------------------------------------
__global__ __launch_bounds__(TPB) void node_mlp_kernel(
    const float* __restrict__ h,  const float* __restrict__ x,
    const float* __restrict__ R0, const float* __restrict__ mi1,
    const int* __restrict__ cnt,
    const float* __restrict__ W1n, const float* __restrict__ b1n,
    const float* __restrict__ W2n, const float* __restrict__ b2n,
    float* __restrict__ out_h, float* __restrict__ out_x, int N)
{
    __shared__ float in_s[NB][D];
    __shared__ float t_s[NB][D];

    const int tid  = threadIdx.x;
    const int cg   = tid & 31;
    const int ng   = tid >> 5;
    const int j0   = cg * 4;
    const int base = blockIdx.x * NB;

    {   // x passthrough: 3 floats per node
        const int xi = blockIdx.x * (NB * 3) + tid;
        if (tid < NB * 3 && xi < N * 3) out_x[xi] = x[xi];
    }

    const float4 b1v = *reinterpret_cast<const float4*>(&b1n[j0]);
    const float4 b2v = *reinterpret_cast<const float4*>(&b2n[j0]);

    for (int r = 0; r < 3; ++r) {
        // stage input row r
        for (int idx = tid; idx < NB * (D / 4); idx += TPB) {
            int n = idx >> 5, k = (idx & 31) << 2;
            int node = base + n; if (node >= N) node = N - 1;
            const size_t g = (size_t)node * D + k;
            float4 v;
            if (r == 0) {
                v = *reinterpret_cast<const float4*>(&R0[g]);
                const float c = (float)cnt[node];
                v.x *= c; v.y *= c; v.z *= c; v.w *= c;
            } else if (r == 1) {
                v = *reinterpret_cast<const float4*>(&mi1[g]);
            } else {
                v = *reinterpret_cast<const float4*>(&h[g]);
            }
            *reinterpret_cast<float4*>(&in_s[n][k]) = v;
        }
        __syncthreads();

        const float* __restrict__ W1 = W1n + (size_t)((r == 2) ? D * D : 0);

        float acc[NPG][4] = {};
        for (int k = 0; k < D; k += 4) {
            const float4 w0 = *reinterpret_cast<const float4*>(&W1[(k + 0) * D + j0]);
            const float4 w1 = *reinterpret_cast<const float4*>(&W1[(k + 1) * D + j0]);
            const float4 w2 = *reinterpret_cast<const float4*>(&W1[(k + 2) * D + j0]);
            const float4 w3 = *reinterpret_cast<const float4*>(&W1[(k + 3) * D + j0]);
            #pragma unroll
            for (int t = 0; t < NPG; ++t) {
                const float4 hv = *reinterpret_cast<const float4*>(&in_s[ng * NPG + t][k]);
                acc[t][0] += hv.x * w0.x + hv.y * w1.x + hv.z * w2.x + hv.w * w3.x;
                acc[t][1] += hv.x * w0.y + hv.y * w1.y + hv.z * w2.y + hv.w * w3.y;
                acc[t][2] += hv.x * w0.z + hv.y * w1.z + hv.z * w2.z + hv.w * w3.z;
                acc[t][3] += hv.x * w0.w + hv.y * w1.w + hv.z * w2.w + hv.w * w3.w;
            }
        }
        __syncthreads();
        #pragma unroll
        for (int t = 0; t < NPG; ++t) {
            float4 tv;
            tv.x = fmaxf(acc[t][0] + b1v.x, 0.f);
            tv.y = fmaxf(acc[t][1] + b1v.y, 0.f);
            tv.z = fmaxf(acc[t][2] + b1v.z, 0.f);
            tv.w = fmaxf(acc[t][3] + b1v.w, 0.f);
            *reinterpret_cast<float4*>(&t_s[ng * NPG + t][j0]) = tv;
        }
        __syncthreads();

        float o[NPG][4] = {};
        for (int k = 0; k < D; k += 4) {
            const float4 w0 = *reinterpret_cast<const float4*>(&W2n[(k + 0) * D + j0]);
            const float4 w1 = *reinterpret_cast<const float4*>(&W2n[(k + 1) * D + j0]);
            const float4 w2 = *reinterpret_cast<const float4*>(&W2n[(k + 2) * D + j0]);
            const float4 w3 = *reinterpret_cast<const float4*>(&W2n[(k + 3) * D + j0]);
            #pragma unroll
            for (int t = 0; t < NPG; ++t) {
                const float4 tv = *reinterpret_cast<const float4*>(&t_s[ng * NPG + t][k]);
                o[t][0] += tv.x * w0.x + tv.y * w1.x + tv.z * w2.x + tv.w * w3.x;
                o[t][1] += tv.x * w0.y + tv.y * w1.y + tv.z * w2.y + tv.w * w3.y;
                o[t][2] += tv.x * w0.z + tv.y * w1.z + tv.z * w2.z + tv.w * w3.z;
                o[t][3] += tv.x * w0.w + tv.y * w1.w + tv.z * w2.w + tv.w * w3.w;
            }
        }

        #pragma unroll
        for (int t = 0; t < NPG; ++t) {
            const int node = base + ng * NPG + t;
            if (node < N) {
                const float4 hres = *reinterpret_cast<const float4*>(&h[(size_t)node * D + j0]);
                const float4 ov = { o[t][0] + b2v.x + hres.x,
                                    o[t][1] + b2v.y + hres.y,
                                    o[t][2] + b2v.z + hres.z,
                                    o[t][3] + b2v.w + hres.w };
                *reinterpret_cast<float4*>(&out_h[((size_t)node * 3 + r) * D + j0]) = ov;
            }
        }
        __syncthreads();
    }
}

// ---------------------------------------------------------------------------
extern "C" void kernel_launch(void* const* d_in, const int* in_sizes, int n_in,
                              void* d_out, int out_size, void* d_ws, size_t ws_size,
                              hipStream_t stream)
{
    const float* h   = (const float*)d_in[0];
    const float* x   = (const float*)d_in[1];
    const int*   ei  = (const int*)d_in[2];
    const float* W1e = (const float*)d_in[3];
    const float* b1e = (const float*)d_in[4];
    const float* W2e = (const float*)d_in[5];
    const float* b2e = (const float*)d_in[6];
    const float* Wg  = (const float*)d_in[7];
    const float* bg  = (const float*)d_in[8];
    const float* W1n = (const float*)d_in[9];
    const float* b1n = (const float*)d_in[10];
    const float* W2n = (const float*)d_in[11];
    const float* b2n = (const float*)d_in[12];

    const int N = in_sizes[0] / D;   // h is [N,1,D]
    const int E = in_sizes[2] / 2;   // edge_index is [2,E]

    // workspace layout: R0 | Q1 | mi1 | cnt | off | cur | bucket
    float* R0     = (float*)d_ws;
    float* Q1     = R0 + (size_t)N * D;
    float* mi1    = Q1 + (size_t)N * D;
    int*   cnt    = (int*)(mi1 + (size_t)N * D);
    int*   off    = cnt + N;
    int*   cur    = off + N;
    int*   bucket = cur + N;

    float* out_h = (float*)d_out;                 // [N,3,D]
    float* out_x = out_h + (size_t)N * 3 * D;     // [N,3]

    hipMemsetAsync(cnt, 0, (size_t)N * sizeof(int), stream);

    const int nblocks = (N + NB - 1) / NB;
    node_pre_kernel<<<nblocks, TPB, 0, stream>>>(h, W1e, b1e, W2e, b2e, Wg, bg, R0, Q1, N);
    hist_kernel<<<(E + 255) / 256, 256, 0, stream>>>(ei, E, cnt);
    scan_kernel<<<1, 1024, 0, stream>>>(cnt, off, cur, N);
    fill_kernel<<<(E + 255) / 256, 256, 0, stream>>>(ei, E, cur, bucket);
    gather_kernel<<<(N + 3) / 4, 256, 0, stream>>>(bucket, off, cnt, Q1, mi1, N);
    node_mlp_kernel<<<nblocks, TPB, 0, stream>>>(h, x, R0, mi1, cnt, W1n, b1n, W2n, b2n,
                                                 out_h, out_x, N);
}

// Round 3
// 222.080 us; speedup vs baseline: 2.4351x; 1.0927x over previous
//
#include <hip/hip_runtime.h>

#define D 128

typedef __attribute__((ext_vector_type(8))) short bf16x8;
typedef __attribute__((ext_vector_type(4))) float f32x4;

__device__ __forceinline__ float sigmoidf(float v) {
    return 1.0f / (1.0f + __expf(-v));
}

__device__ __forceinline__ unsigned short f2bf(float x) {
    union { float f; unsigned u; } c; c.f = x;
    unsigned r = (c.u + 0x7fffu + ((c.u >> 16) & 1u)) >> 16;
    return (unsigned short)r;
}
__device__ __forceinline__ float bf2f(unsigned short b) {
    union { unsigned u; float f; } c; c.u = ((unsigned)b) << 16;
    return c.f;
}
__device__ __forceinline__ float bflo(unsigned u) {
    union { unsigned v; float f; } c; c.v = u << 16; return c.f;
}
__device__ __forceinline__ float bfhi(unsigned u) {
    union { unsigned v; float f; } c; c.v = u & 0xffff0000u; return c.f;
}

#define LROW 132   // padded LDS row stride (floats); 16B-aligned, 2-way-max bank aliasing

// Build split A-fragments (hi/lo bf16) for a 32-row tile from padded LDS.
// A-frag layout for mfma_f32_16x16x32_bf16: row = lane&15 (+16*rt), k = ks*32 + (lane>>4)*8 + e.
__device__ __forceinline__ void build_frags(const float* __restrict__ s, int lane,
                                            bf16x8 ah[4][2], bf16x8 al[4][2])
{
    #pragma unroll
    for (int ks = 0; ks < 4; ++ks) {
        #pragma unroll
        for (int rt = 0; rt < 2; ++rt) {
            const float* p = s + (rt * 16 + (lane & 15)) * LROW + ks * 32 + (lane >> 4) * 8;
            float f[8];
            *reinterpret_cast<float4*>(&f[0]) = *reinterpret_cast<const float4*>(p);
            *reinterpret_cast<float4*>(&f[4]) = *reinterpret_cast<const float4*>(p + 4);
            bf16x8 h, l;
            #pragma unroll
            for (int e = 0; e < 8; ++e) {
                const float v = f[e];
                const unsigned short hb = f2bf(v);
                h[e] = (short)hb;
                l[e] = (short)f2bf(v - bf2f(hb));
            }
            ah[ks][rt] = h; al[ks][rt] = l;
        }
    }
}

// One 32x128 = (32x128)@(128x128) layer via MFMA with 3-product split.
// WbM: repacked weight fragments [ct][ks][hi/lo][lane][8] bf16.
__device__ __forceinline__ void mfma_layer(const short* __restrict__ WbM, int lane,
                                           const bf16x8 ah[4][2], const bf16x8 al[4][2],
                                           f32x4 acc[8][2])
{
    #pragma unroll
    for (int ct = 0; ct < 8; ++ct) {
        #pragma unroll
        for (int ks = 0; ks < 4; ++ks) {
            const short* wp = WbM + (ct * 4 + ks) * 1024 + lane * 8;
            const bf16x8 bh = *reinterpret_cast<const bf16x8*>(wp);
            const bf16x8 bl = *reinterpret_cast<const bf16x8*>(wp + 512);
            #pragma unroll
            for (int rt = 0; rt < 2; ++rt) {
                acc[ct][rt] = __builtin_amdgcn_mfma_f32_16x16x32_bf16(ah[ks][rt], bh, acc[ct][rt], 0, 0, 0);
                acc[ct][rt] = __builtin_amdgcn_mfma_f32_16x16x32_bf16(al[ks][rt], bh, acc[ct][rt], 0, 0, 0);
                acc[ct][rt] = __builtin_amdgcn_mfma_f32_16x16x32_bf16(ah[ks][rt], bl, acc[ct][rt], 0, 0, 0);
            }
        }
    }
}

// ---------------------------------------------------------------------------
// Weight repack: 6 fp32 128x128 matrices -> hi/lo bf16 B-fragments.
// B-frag layout: k = ks*32 + (lane>>4)*8 + e, j = ct*16 + (lane&15).
// ---------------------------------------------------------------------------
__global__ __launch_bounds__(256) void repack_kernel(
    const float* __restrict__ W1e, const float* __restrict__ W2e,
    const float* __restrict__ W1n, const float* __restrict__ W2n,
    short* __restrict__ Wb)
{
    const int gid = blockIdx.x * 256 + threadIdx.x;
    if (gid >= 6 * 8 * 4 * 64) return;
    const int lane = gid & 63;
    int t = gid >> 6;
    const int ks = t & 3; t >>= 2;
    const int ct = t & 7;
    const int m  = t >> 3;
    const float* src;
    switch (m) {
        case 0: src = W1e;             break;
        case 1: src = W1e + 128 * 128; break;
        case 2: src = W2e;             break;
        case 3: src = W1n;             break;
        case 4: src = W1n + 128 * 128; break;
        default: src = W2n;            break;
    }
    const int j  = ct * 16 + (lane & 15);
    const int k0 = ks * 32 + (lane >> 4) * 8;
    bf16x8 hi, lo;
    #pragma unroll
    for (int e = 0; e < 8; ++e) {
        const float w = src[(size_t)(k0 + e) * 128 + j];
        const unsigned short hb = f2bf(w);
        hi[e] = (short)hb;
        lo[e] = (short)f2bf(w - bf2f(hb));
    }
    short* dst = Wb + (size_t)m * 32768 + (ct * 4 + ks) * 1024 + lane * 8;
    *reinterpret_cast<bf16x8*>(dst)       = hi;
    *reinterpret_cast<bf16x8*>(dst + 512) = lo;
}

// ---------------------------------------------------------------------------
// Kernel 1: per-node edge-MLP precompute (MFMA). 1 wave = 32 nodes.
//   P0 -> R0 (fp32), P1 -> Q1 (bf16)
// ---------------------------------------------------------------------------
__global__ __launch_bounds__(64) void node_pre_mfma(
    const float* __restrict__ h, const short* __restrict__ Wb,
    const float* __restrict__ b1e, const float* __restrict__ b2e,
    const float* __restrict__ Wg,  const float* __restrict__ bg,
    float* __restrict__ R0, unsigned short* __restrict__ Q1b, int N)
{
    __shared__ float h_s[32 * LROW];
    __shared__ float t_s[32 * LROW];
    const int lane = threadIdx.x;
    const int base = blockIdx.x * 32;

    for (int idx = lane; idx < 32 * 32; idx += 64) {
        const int row = idx >> 5, c4 = (idx & 31) << 2;
        int node = base + row; if (node >= N) node = N - 1;
        *reinterpret_cast<float4*>(&h_s[row * LROW + c4]) =
            *reinterpret_cast<const float4*>(&h[(size_t)node * D + c4]);
    }
    __syncthreads();

    float b1v[8], b2v[8], wgv[8];
    #pragma unroll
    for (int ct = 0; ct < 8; ++ct) {
        const int j = ct * 16 + (lane & 15);
        b1v[ct] = b1e[j]; b2v[ct] = b2e[j]; wgv[ct] = Wg[j];
    }
    const float bgv = bg[0];

    bf16x8 ah[4][2], al[4][2];
    build_frags(h_s, lane, ah, al);

    for (int hf = 0; hf < 2; ++hf) {
        f32x4 acc[8][2];
        #pragma unroll
        for (int ct = 0; ct < 8; ++ct)
            #pragma unroll
            for (int rt = 0; rt < 2; ++rt) acc[ct][rt] = (f32x4){0.f, 0.f, 0.f, 0.f};
        mfma_layer(Wb + (size_t)hf * 32768, lane, ah, al, acc);

        __syncthreads();
        #pragma unroll
        for (int ct = 0; ct < 8; ++ct)
            #pragma unroll
            for (int rt = 0; rt < 2; ++rt)
                #pragma unroll
                for (int r = 0; r < 4; ++r) {
                    const int row = rt * 16 + (lane >> 4) * 4 + r;
                    t_s[row * LROW + ct * 16 + (lane & 15)] = fmaxf(acc[ct][rt][r] + b1v[ct], 0.f);
                }
        __syncthreads();

        bf16x8 th[4][2], tl[4][2];
        build_frags(t_s, lane, th, tl);
        f32x4 p[8][2];
        #pragma unroll
        for (int ct = 0; ct < 8; ++ct)
            #pragma unroll
            for (int rt = 0; rt < 2; ++rt) p[ct][rt] = (f32x4){0.f, 0.f, 0.f, 0.f};
        mfma_layer(Wb + (size_t)2 * 32768, lane, th, tl, p);

        // gate
        float g[2][4];
        #pragma unroll
        for (int rt = 0; rt < 2; ++rt) {
            float part[4] = {0.f, 0.f, 0.f, 0.f};
            #pragma unroll
            for (int ct = 0; ct < 8; ++ct)
                #pragma unroll
                for (int r = 0; r < 4; ++r)
                    part[r] += (p[ct][rt][r] + b2v[ct]) * wgv[ct];
            #pragma unroll
            for (int r = 0; r < 4; ++r) {
                float v = part[r];
                #pragma unroll
                for (int m = 1; m <= 8; m <<= 1) v += __shfl_xor(v, m, 64);
                g[rt][r] = sigmoidf(v + bgv);
            }
        }

        // store
        #pragma unroll
        for (int ct = 0; ct < 8; ++ct)
            #pragma unroll
            for (int rt = 0; rt < 2; ++rt)
                #pragma unroll
                for (int r = 0; r < 4; ++r) {
                    const int node = base + rt * 16 + (lane >> 4) * 4 + r;
                    if (node < N) {
                        const int j = ct * 16 + (lane & 15);
                        const float val = (p[ct][rt][r] + b2v[ct]) * g[rt][r];
                        if (hf == 0) R0[(size_t)node * D + j] = val;
                        else         Q1b[(size_t)node * D + j] = f2bf(val);
                    }
                }
    }
}

// ---------------------------------------------------------------------------
// CSR build
// ---------------------------------------------------------------------------
__global__ __launch_bounds__(256) void hist_kernel(
    const int* __restrict__ ei, int E, int* __restrict__ cnt)
{
    const int e = blockIdx.x * 256 + threadIdx.x;
    if (e < E) atomicAdd(&cnt[ei[E + e]], 1);
}

__global__ __launch_bounds__(1024) void scan_kernel(
    const int* __restrict__ cnt, int* __restrict__ off, int* __restrict__ cur, int N)
{
    __shared__ int wsum[16];
    const int tid = threadIdx.x, lane = tid & 63, wid = tid >> 6;
    const int IT = (N + 1023) >> 10;   // assumes <= 32
    const int base = tid * IT;
    int v[32];
    int run = 0;
    #pragma unroll
    for (int u = 0; u < 32; ++u) {
        if (u < IT) {
            const int i = base + u;
            run += (i < N) ? cnt[i] : 0;
            v[u] = run;
        }
    }
    const int tot = run;
    int incl = tot;
    #pragma unroll
    for (int o = 1; o < 64; o <<= 1) {
        const int u2 = __shfl_up(incl, o, 64);
        if (lane >= o) incl += u2;
    }
    if (lane == 63) wsum[wid] = incl;
    __syncthreads();
    if (tid < 16) {
        int w = wsum[tid];
        #pragma unroll
        for (int o = 1; o < 16; o <<= 1) {
            const int u2 = __shfl_up(w, o, 16);
            if (tid >= o) w += u2;
        }
        wsum[tid] = w;
    }
    __syncthreads();
    const int tbase = ((wid > 0) ? wsum[wid - 1] : 0) + (incl - tot);
    #pragma unroll
    for (int u = 0; u < 32; ++u) {
        if (u < IT) {
            const int i = base + u;
            if (i < N) {
                const int ex = tbase + ((u > 0) ? v[u - 1] : 0);
                off[i] = ex; cur[i] = ex;
            }
        }
    }
}

__global__ __launch_bounds__(256) void fill_kernel(
    const int* __restrict__ ei, int E, int* __restrict__ cur, int* __restrict__ bucket)
{
    const int e = blockIdx.x * 256 + threadIdx.x;
    if (e < E) {
        const int pos = atomicAdd(&cur[ei[E + e]], 1);
        bucket[pos] = ei[e];
    }
}

// ---------------------------------------------------------------------------
// Gather: mi1[n] = sum_{dst==n} Q1[src] (Q1 in bf16). One wave per node,
// 4 edge slots x 16 lanes (8 channels each).
// ---------------------------------------------------------------------------
__global__ __launch_bounds__(256) void gather_kernel(
    const int* __restrict__ bucket, const int* __restrict__ off,
    const int* __restrict__ cntv, const unsigned short* __restrict__ Q1b,
    float* __restrict__ mi1, int N)
{
    const int n = blockIdx.x * 4 + (threadIdx.x >> 6);
    if (n >= N) return;
    const int lane = threadIdx.x & 63;
    const int slot = lane >> 4, c16 = lane & 15;
    const int beg = off[n], deg = cntv[n];
    float a[8] = {0.f, 0.f, 0.f, 0.f, 0.f, 0.f, 0.f, 0.f};
    for (int i = slot; i < deg; i += 4) {
        const int s = bucket[beg + i];
        const uint4 q = *reinterpret_cast<const uint4*>(Q1b + (size_t)s * D + c16 * 8);
        a[0] += bflo(q.x); a[1] += bfhi(q.x);
        a[2] += bflo(q.y); a[3] += bfhi(q.y);
        a[4] += bflo(q.z); a[5] += bfhi(q.z);
        a[6] += bflo(q.w); a[7] += bfhi(q.w);
    }
    #pragma unroll
    for (int e = 0; e < 8; ++e) {
        a[e] += __shfl_xor(a[e], 16, 64);
        a[e] += __shfl_xor(a[e], 32, 64);
    }
    if (slot == 0) {
        const float4 v0 = {a[0], a[1], a[2], a[3]};
        const float4 v1 = {a[4], a[5], a[6], a[7]};
        *reinterpret_cast<float4*>(&mi1[(size_t)n * D + c16 * 8])     = v0;
        *reinterpret_cast<float4*>(&mi1[(size_t)n * D + c16 * 8 + 4]) = v1;
    }
}

// ---------------------------------------------------------------------------
// Kernel 3: node MLP + residual + output (MFMA). 1 wave = 32 nodes.
// ---------------------------------------------------------------------------
__global__ __launch_bounds__(64) void node_mlp_mfma(
    const float* __restrict__ h,  const float* __restrict__ x,
    const float* __restrict__ R0, const float* __restrict__ mi1,
    const int* __restrict__ cnt,  const short* __restrict__ Wb,
    const float* __restrict__ b1n, const float* __restrict__ b2n,
    float* __restrict__ out_h, float* __restrict__ out_x, int N)
{
    __shared__ float h_s[32 * LROW];
    __shared__ float io_s[32 * LROW];
    __shared__ float t_s[32 * LROW];
    const int lane = threadIdx.x;
    const int base = blockIdx.x * 32;

    for (int i = lane; i < 96; i += 64) {
        const int xi = base * 3 + i;
        if (xi < N * 3) out_x[xi] = x[xi];
    }

    for (int idx = lane; idx < 32 * 32; idx += 64) {
        const int row = idx >> 5, c4 = (idx & 31) << 2;
        int node = base + row; if (node >= N) node = N - 1;
        *reinterpret_cast<float4*>(&h_s[row * LROW + c4]) =
            *reinterpret_cast<const float4*>(&h[(size_t)node * D + c4]);
    }
    __syncthreads();

    float b1v[8], b2v[8];
    #pragma unroll
    for (int ct = 0; ct < 8; ++ct) {
        const int j = ct * 16 + (lane & 15);
        b1v[ct] = b1n[j]; b2v[ct] = b2n[j];
    }

    for (int r = 0; r < 3; ++r) {
        if (r < 2) {
            for (int idx = lane; idx < 32 * 32; idx += 64) {
                const int row = idx >> 5, c4 = (idx & 31) << 2;
                int node = base + row; if (node >= N) node = N - 1;
                const size_t g = (size_t)node * D + c4;
                float4 v;
                if (r == 0) {
                    v = *reinterpret_cast<const float4*>(&R0[g]);
                    const float c = (float)cnt[node];
                    v.x *= c; v.y *= c; v.z *= c; v.w *= c;
                } else {
                    v = *reinterpret_cast<const float4*>(&mi1[g]);
                }
                *reinterpret_cast<float4*>(&io_s[row * LROW + c4]) = v;
            }
            __syncthreads();
        }

        bf16x8 ah[4][2], al[4][2];
        build_frags((r == 2) ? h_s : io_s, lane, ah, al);

        f32x4 acc[8][2];
        #pragma unroll
        for (int ct = 0; ct < 8; ++ct)
            #pragma unroll
            for (int rt = 0; rt < 2; ++rt) acc[ct][rt] = (f32x4){0.f, 0.f, 0.f, 0.f};
        mfma_layer(Wb + (size_t)((r == 2) ? 4 : 3) * 32768, lane, ah, al, acc);

        __syncthreads();
        #pragma unroll
        for (int ct = 0; ct < 8; ++ct)
            #pragma unroll
            for (int rt = 0; rt < 2; ++rt)
                #pragma unroll
                for (int rr = 0; rr < 4; ++rr) {
                    const int row = rt * 16 + (lane >> 4) * 4 + rr;
                    t_s[row * LROW + ct * 16 + (lane & 15)] = fmaxf(acc[ct][rt][rr] + b1v[ct], 0.f);
                }
        __syncthreads();

        bf16x8 th[4][2], tl[4][2];
        build_frags(t_s, lane, th, tl);
        f32x4 o[8][2];
        #pragma unroll
        for (int ct = 0; ct < 8; ++ct)
            #pragma unroll
            for (int rt = 0; rt < 2; ++rt) o[ct][rt] = (f32x4){0.f, 0.f, 0.f, 0.f};
        mfma_layer(Wb + (size_t)5 * 32768, lane, th, tl, o);

        #pragma unroll
        for (int ct = 0; ct < 8; ++ct)
            #pragma unroll
            for (int rt = 0; rt < 2; ++rt)
                #pragma unroll
                for (int rr = 0; rr < 4; ++rr) {
                    const int row = rt * 16 + (lane >> 4) * 4 + rr;
                    const int node = base + row;
                    if (node < N) {
                        const int j = ct * 16 + (lane & 15);
                        const float val = o[ct][rt][rr] + b2v[ct] + h_s[row * LROW + j];
                        out_h[((size_t)node * 3 + r) * D + j] = val;
                    }
                }
        __syncthreads();
    }
}

// ---------------------------------------------------------------------------
extern "C" void kernel_launch(void* const* d_in, const int* in_sizes, int n_in,
                              void* d_out, int out_size, void* d_ws, size_t ws_size,
                              hipStream_t stream)
{
    const float* h   = (const float*)d_in[0];
    const float* x   = (const float*)d_in[1];
    const int*   ei  = (const int*)d_in[2];
    const float* W1e = (const float*)d_in[3];
    const float* b1e = (const float*)d_in[4];
    const float* W2e = (const float*)d_in[5];
    const float* b2e = (const float*)d_in[6];
    const float* Wg  = (const float*)d_in[7];
    const float* bg  = (const float*)d_in[8];
    const float* W1n = (const float*)d_in[9];
    const float* b1n = (const float*)d_in[10];
    const float* W2n = (const float*)d_in[11];
    const float* b2n = (const float*)d_in[12];

    const int N = in_sizes[0] / D;
    const int E = in_sizes[2] / 2;

    // workspace: R0 | mi1 | Q1b(bf16) | Wb | cnt | off | cur | bucket
    float*          R0   = (float*)d_ws;
    float*          mi1  = R0 + (size_t)N * D;
    unsigned short* Q1b  = (unsigned short*)(mi1 + (size_t)N * D);
    short*          Wb   = (short*)(Q1b + (size_t)N * D);
    int*            cnt  = (int*)(Wb + 6 * 32768);
    int*            off  = cnt + N;
    int*            cur  = off + N;
    int*            bucket = cur + N;

    float* out_h = (float*)d_out;                 // [N,3,D]
    float* out_x = out_h + (size_t)N * 3 * D;     // [N,3]

    hipMemsetAsync(cnt, 0, (size_t)N * sizeof(int), stream);

    repack_kernel<<<48, 256, 0, stream>>>(W1e, W2e, W1n, W2n, Wb);
    hist_kernel<<<(E + 255) / 256, 256, 0, stream>>>(ei, E, cnt);
    scan_kernel<<<1, 1024, 0, stream>>>(cnt, off, cur, N);
    fill_kernel<<<(E + 255) / 256, 256, 0, stream>>>(ei, E, cur, bucket);
    node_pre_mfma<<<(N + 31) / 32, 64, 0, stream>>>(h, Wb, b1e, b2e, Wg, bg, R0, Q1b, N);
    gather_kernel<<<(N + 3) / 4, 256, 0, stream>>>(bucket, off, cnt, Q1b, mi1, N);
    node_mlp_mfma<<<(N + 31) / 32, 64, 0, stream>>>(h, x, R0, mi1, cnt, Wb, b1n, b2n,
                                                    out_h, out_x, N);
}

// Round 4
// 156.224 us; speedup vs baseline: 3.4617x; 1.4216x over previous
//
#include <hip/hip_runtime.h>

#define D  128
#define SP 136   // LDS activation-plane row stride in shorts (272B: 16B-aligned, 2-way max aliasing)

typedef __attribute__((ext_vector_type(8))) short bf16x8;
typedef __attribute__((ext_vector_type(4))) float f32x4;
typedef unsigned short u16;

__device__ __forceinline__ float sigmoidf(float v) { return 1.0f / (1.0f + __expf(-v)); }

__device__ __forceinline__ u16 f2bf(float x) {
    union { float f; unsigned u; } c; c.f = x;
    return (u16)((c.u + 0x7fffu + ((c.u >> 16) & 1u)) >> 16);
}
__device__ __forceinline__ float bf2f(u16 b) {
    union { unsigned u; float f; } c; c.u = ((unsigned)b) << 16; return c.f;
}
__device__ __forceinline__ float bflo(unsigned u) {
    union { unsigned v; float f; } c; c.v = u << 16; return c.f;
}
__device__ __forceinline__ float bfhi(unsigned u) {
    union { unsigned v; float f; } c; c.v = u & 0xffff0000u; return c.f;
}

// ---------------------------------------------------------------------------
// One 32x128 @ 128x128 half-layer: this wave computes 4 column-tiles
// (ctbase..ctbase+3) for all 32 rows, 3-product hi/lo split.
// A-frag: row = rt*16 + (lane&15), k = ks*32 + (lane>>4)*8 + e  (verified r3)
// ---------------------------------------------------------------------------
__device__ __forceinline__ void layer_mfma(
    const u16* __restrict__ a_hi, const u16* __restrict__ a_lo,
    const short* __restrict__ WbM, int lane, int ctbase, f32x4 acc[4][2])
{
    #pragma unroll
    for (int ks = 0; ks < 4; ++ks) {
        bf16x8 ah[2], al[2];
        #pragma unroll
        for (int rt = 0; rt < 2; ++rt) {
            const int o = (rt * 16 + (lane & 15)) * SP + ks * 32 + (lane >> 4) * 8;
            ah[rt] = *reinterpret_cast<const bf16x8*>(a_hi + o);
            al[rt] = *reinterpret_cast<const bf16x8*>(a_lo + o);
        }
        #pragma unroll
        for (int c = 0; c < 4; ++c) {
            const short* wp = WbM + ((ctbase + c) * 4 + ks) * 1024 + lane * 8;
            const bf16x8 bh = *reinterpret_cast<const bf16x8*>(wp);
            const bf16x8 bl = *reinterpret_cast<const bf16x8*>(wp + 512);
            #pragma unroll
            for (int rt = 0; rt < 2; ++rt) {
                acc[c][rt] = __builtin_amdgcn_mfma_f32_16x16x32_bf16(ah[rt], bl, acc[c][rt], 0, 0, 0);
                acc[c][rt] = __builtin_amdgcn_mfma_f32_16x16x32_bf16(al[rt], bh, acc[c][rt], 0, 0, 0);
                acc[c][rt] = __builtin_amdgcn_mfma_f32_16x16x32_bf16(ah[rt], bh, acc[c][rt], 0, 0, 0);
            }
        }
    }
}

// relu(acc + b1) -> split hi/lo planes.  C/D: row = rt*16 + (lane>>4)*4 + rr,
// col = ct*16 + (lane&15)  (verified r3)
__device__ __forceinline__ void store_relu_split(
    const f32x4 acc[4][2], const float b1v[4],
    u16* __restrict__ t_hi, u16* __restrict__ t_lo, int lane, int ctbase)
{
    #pragma unroll
    for (int c = 0; c < 4; ++c)
        #pragma unroll
        for (int rt = 0; rt < 2; ++rt)
            #pragma unroll
            for (int rr = 0; rr < 4; ++rr) {
                const int row = rt * 16 + (lane >> 4) * 4 + rr;
                const int j   = (ctbase + c) * 16 + (lane & 15);
                const float v = fmaxf(acc[c][rt][rr] + b1v[c], 0.f);
                const u16 hb = f2bf(v);
                t_hi[row * SP + j] = hb;
                t_lo[row * SP + j] = f2bf(v - bf2f(hb));
            }
}

// ---------------------------------------------------------------------------
// Weight repack: 6 fp32 128x128 matrices -> hi/lo bf16 B-fragments (as r3).
// ---------------------------------------------------------------------------
__global__ __launch_bounds__(256) void repack_kernel(
    const float* __restrict__ W1e, const float* __restrict__ W2e,
    const float* __restrict__ W1n, const float* __restrict__ W2n,
    short* __restrict__ Wb)
{
    const int gid = blockIdx.x * 256 + threadIdx.x;
    if (gid >= 6 * 8 * 4 * 64) return;
    const int lane = gid & 63;
    int t = gid >> 6;
    const int ks = t & 3; t >>= 2;
    const int ct = t & 7;
    const int m  = t >> 3;
    const float* src;
    switch (m) {
        case 0: src = W1e;             break;
        case 1: src = W1e + 128 * 128; break;
        case 2: src = W2e;             break;
        case 3: src = W1n;             break;
        case 4: src = W1n + 128 * 128; break;
        default: src = W2n;            break;
    }
    const int j  = ct * 16 + (lane & 15);
    const int k0 = ks * 32 + (lane >> 4) * 8;
    bf16x8 hi, lo;
    #pragma unroll
    for (int e = 0; e < 8; ++e) {
        const float w = src[(size_t)(k0 + e) * 128 + j];
        const u16 hb = f2bf(w);
        hi[e] = (short)hb;
        lo[e] = (short)f2bf(w - bf2f(hb));
    }
    short* dst = Wb + (size_t)m * 32768 + (ct * 4 + ks) * 1024 + lane * 8;
    *reinterpret_cast<bf16x8*>(dst)       = hi;
    *reinterpret_cast<bf16x8*>(dst + 512) = lo;
}

// ---------------------------------------------------------------------------
// Kernel 1: per-node edge-MLP precompute. Block = 128 thr (2 waves), 32 nodes.
// hf split across blocks (grid = 2*ntiles): hf=0 -> R0 fp32, hf=1 -> Q1 bf16.
// ---------------------------------------------------------------------------
__global__ __launch_bounds__(128) void node_pre_mfma(
    const float* __restrict__ h, const short* __restrict__ Wb,
    const float* __restrict__ b1e, const float* __restrict__ b2e,
    const float* __restrict__ Wg,  const float* __restrict__ bg,
    float* __restrict__ R0, u16* __restrict__ Q1b, int N)
{
    __shared__ u16 a_hi[32 * SP], a_lo[32 * SP];
    __shared__ u16 t_hi[32 * SP], t_lo[32 * SP];
    __shared__ float red_s[2][32];

    const int tid  = threadIdx.x, lane = tid & 63, w = tid >> 6;
    const int hf   = blockIdx.x & 1;
    const int base = (blockIdx.x >> 1) * 32;
    const int ctbase = w * 4;

    // stage h, pre-split into hi/lo planes
    for (int idx = tid; idx < 32 * 32; idx += 128) {
        const int row = idx >> 5, c4 = (idx & 31) << 2;
        int node = base + row; if (node >= N) node = N - 1;
        const float4 v = *reinterpret_cast<const float4*>(&h[(size_t)node * D + c4]);
        ushort4 hi, lo;
        hi.x = f2bf(v.x); lo.x = f2bf(v.x - bf2f(hi.x));
        hi.y = f2bf(v.y); lo.y = f2bf(v.y - bf2f(hi.y));
        hi.z = f2bf(v.z); lo.z = f2bf(v.z - bf2f(hi.z));
        hi.w = f2bf(v.w); lo.w = f2bf(v.w - bf2f(hi.w));
        *reinterpret_cast<ushort4*>(&a_hi[row * SP + c4]) = hi;
        *reinterpret_cast<ushort4*>(&a_lo[row * SP + c4]) = lo;
    }
    __syncthreads();

    float b1v[4], b2v[4], wgv[4];
    #pragma unroll
    for (int c = 0; c < 4; ++c) {
        const int j = (ctbase + c) * 16 + (lane & 15);
        b1v[c] = b1e[j]; b2v[c] = b2e[j]; wgv[c] = Wg[j];
    }
    const float bgv = bg[0];

    f32x4 acc[4][2];
    #pragma unroll
    for (int c = 0; c < 4; ++c)
        #pragma unroll
        for (int rt = 0; rt < 2; ++rt) acc[c][rt] = (f32x4){0.f, 0.f, 0.f, 0.f};
    layer_mfma(a_hi, a_lo, Wb + (size_t)hf * 32768, lane, ctbase, acc);
    store_relu_split(acc, b1v, t_hi, t_lo, lane, ctbase);
    __syncthreads();

    f32x4 p[4][2];
    #pragma unroll
    for (int c = 0; c < 4; ++c)
        #pragma unroll
        for (int rt = 0; rt < 2; ++rt) p[c][rt] = (f32x4){0.f, 0.f, 0.f, 0.f};
    layer_mfma(t_hi, t_lo, Wb + (size_t)2 * 32768, lane, ctbase, p);

    // gate partial over this wave's 64 columns, reduced within 16-lane groups
    #pragma unroll
    for (int rt = 0; rt < 2; ++rt)
        #pragma unroll
        for (int rr = 0; rr < 4; ++rr) {
            float part = 0.f;
            #pragma unroll
            for (int c = 0; c < 4; ++c) part += (p[c][rt][rr] + b2v[c]) * wgv[c];
            #pragma unroll
            for (int m = 1; m <= 8; m <<= 1) part += __shfl_xor(part, m, 64);
            if ((lane & 15) == 0)
                red_s[w][rt * 16 + (lane >> 4) * 4 + rr] = part;
        }
    __syncthreads();

    float g[2][4];
    #pragma unroll
    for (int rt = 0; rt < 2; ++rt)
        #pragma unroll
        for (int rr = 0; rr < 4; ++rr) {
            const int row = rt * 16 + (lane >> 4) * 4 + rr;
            g[rt][rr] = sigmoidf(red_s[0][row] + red_s[1][row] + bgv);
        }

    #pragma unroll
    for (int c = 0; c < 4; ++c)
        #pragma unroll
        for (int rt = 0; rt < 2; ++rt)
            #pragma unroll
            for (int rr = 0; rr < 4; ++rr) {
                const int row  = rt * 16 + (lane >> 4) * 4 + rr;
                const int node = base + row;
                if (node < N) {
                    const int j = (ctbase + c) * 16 + (lane & 15);
                    const float val = (p[c][rt][rr] + b2v[c]) * g[rt][rr];
                    if (hf == 0) R0[(size_t)node * D + j] = val;
                    else         Q1b[(size_t)node * D + j] = f2bf(val);
                }
            }
}

// ---------------------------------------------------------------------------
// CSR build (unchanged)
// ---------------------------------------------------------------------------
__global__ __launch_bounds__(256) void hist_kernel(
    const int* __restrict__ ei, int E, int* __restrict__ cnt)
{
    const int e = blockIdx.x * 256 + threadIdx.x;
    if (e < E) atomicAdd(&cnt[ei[E + e]], 1);
}

__global__ __launch_bounds__(1024) void scan_kernel(
    const int* __restrict__ cnt, int* __restrict__ off, int* __restrict__ cur, int N)
{
    __shared__ int wsum[16];
    const int tid = threadIdx.x, lane = tid & 63, wid = tid >> 6;
    const int IT = (N + 1023) >> 10;   // assumes <= 32
    const int base = tid * IT;
    int v[32];
    int run = 0;
    #pragma unroll
    for (int u = 0; u < 32; ++u) {
        if (u < IT) {
            const int i = base + u;
            run += (i < N) ? cnt[i] : 0;
            v[u] = run;
        }
    }
    const int tot = run;
    int incl = tot;
    #pragma unroll
    for (int o = 1; o < 64; o <<= 1) {
        const int u2 = __shfl_up(incl, o, 64);
        if (lane >= o) incl += u2;
    }
    if (lane == 63) wsum[wid] = incl;
    __syncthreads();
    if (tid < 16) {
        int w = wsum[tid];
        #pragma unroll
        for (int o = 1; o < 16; o <<= 1) {
            const int u2 = __shfl_up(w, o, 16);
            if (tid >= o) w += u2;
        }
        wsum[tid] = w;
    }
    __syncthreads();
    const int tbase = ((wid > 0) ? wsum[wid - 1] : 0) + (incl - tot);
    #pragma unroll
    for (int u = 0; u < 32; ++u) {
        if (u < IT) {
            const int i = base + u;
            if (i < N) {
                const int ex = tbase + ((u > 0) ? v[u - 1] : 0);
                off[i] = ex; cur[i] = ex;
            }
        }
    }
}

__global__ __launch_bounds__(256) void fill_kernel(
    const int* __restrict__ ei, int E, int* __restrict__ cur, int* __restrict__ bucket)
{
    const int e = blockIdx.x * 256 + threadIdx.x;
    if (e < E) {
        const int pos = atomicAdd(&cur[ei[E + e]], 1);
        bucket[pos] = ei[e];
    }
}

// ---------------------------------------------------------------------------
// Gather (unchanged): mi1[n] = sum_{dst==n} Q1[src] (bf16 source)
// ---------------------------------------------------------------------------
__global__ __launch_bounds__(256) void gather_kernel(
    const int* __restrict__ bucket, const int* __restrict__ off,
    const int* __restrict__ cntv, const u16* __restrict__ Q1b,
    float* __restrict__ mi1, int N)
{
    const int n = blockIdx.x * 4 + (threadIdx.x >> 6);
    if (n >= N) return;
    const int lane = threadIdx.x & 63;
    const int slot = lane >> 4, c16 = lane & 15;
    const int beg = off[n], deg = cntv[n];
    float a[8] = {0.f, 0.f, 0.f, 0.f, 0.f, 0.f, 0.f, 0.f};
    for (int i = slot; i < deg; i += 4) {
        const int s = bucket[beg + i];
        const uint4 q = *reinterpret_cast<const uint4*>(Q1b + (size_t)s * D + c16 * 8);
        a[0] += bflo(q.x); a[1] += bfhi(q.x);
        a[2] += bflo(q.y); a[3] += bfhi(q.y);
        a[4] += bflo(q.z); a[5] += bfhi(q.z);
        a[6] += bflo(q.w); a[7] += bfhi(q.w);
    }
    #pragma unroll
    for (int e = 0; e < 8; ++e) {
        a[e] += __shfl_xor(a[e], 16, 64);
        a[e] += __shfl_xor(a[e], 32, 64);
    }
    if (slot == 0) {
        const float4 v0 = {a[0], a[1], a[2], a[3]};
        const float4 v1 = {a[4], a[5], a[6], a[7]};
        *reinterpret_cast<float4*>(&mi1[(size_t)n * D + c16 * 8])     = v0;
        *reinterpret_cast<float4*>(&mi1[(size_t)n * D + c16 * 8 + 4]) = v1;
    }
}

// ---------------------------------------------------------------------------
// Kernel 3: node MLP + residual. Block = 128 thr (2 waves), 32 nodes, one r.
// grid = 3*ntiles: r = blockIdx.x % 3.  row0: cnt*R0, row1: mi1, row2: h.
// ---------------------------------------------------------------------------
__global__ __launch_bounds__(128) void node_mlp_mfma(
    const float* __restrict__ h,  const float* __restrict__ x,
    const float* __restrict__ R0, const float* __restrict__ mi1,
    const int* __restrict__ cnt,  const short* __restrict__ Wb,
    const float* __restrict__ b1n, const float* __restrict__ b2n,
    float* __restrict__ out_h, float* __restrict__ out_x, int N)
{
    __shared__ u16 a_hi[32 * SP], a_lo[32 * SP];
    __shared__ u16 t_hi[32 * SP], t_lo[32 * SP];

    const int tid  = threadIdx.x, lane = tid & 63, w = tid >> 6;
    const int r    = blockIdx.x % 3;
    const int tile = blockIdx.x / 3;
    const int base = tile * 32;
    const int ctbase = w * 4;

    if (r == 0) {   // x passthrough once per tile
        const int xi = tile * 96 + tid;
        if (tid < 96 && xi < N * 3) out_x[xi] = x[xi];
    }

    const float* __restrict__ src = (r == 0) ? R0 : (r == 1) ? mi1 : h;
    for (int idx = tid; idx < 32 * 32; idx += 128) {
        const int row = idx >> 5, c4 = (idx & 31) << 2;
        int node = base + row; if (node >= N) node = N - 1;
        float4 v = *reinterpret_cast<const float4*>(&src[(size_t)node * D + c4]);
        if (r == 0) {
            const float cv = (float)cnt[node];
            v.x *= cv; v.y *= cv; v.z *= cv; v.w *= cv;
        }
        ushort4 hi, lo;
        hi.x = f2bf(v.x); lo.x = f2bf(v.x - bf2f(hi.x));
        hi.y = f2bf(v.y); lo.y = f2bf(v.y - bf2f(hi.y));
        hi.z = f2bf(v.z); lo.z = f2bf(v.z - bf2f(hi.z));
        hi.w = f2bf(v.w); lo.w = f2bf(v.w - bf2f(hi.w));
        *reinterpret_cast<ushort4*>(&a_hi[row * SP + c4]) = hi;
        *reinterpret_cast<ushort4*>(&a_lo[row * SP + c4]) = lo;
    }
    __syncthreads();

    float b1v[4], b2v[4];
    #pragma unroll
    for (int c = 0; c < 4; ++c) {
        const int j = (ctbase + c) * 16 + (lane & 15);
        b1v[c] = b1n[j]; b2v[c] = b2n[j];
    }

    f32x4 acc[4][2];
    #pragma unroll
    for (int c = 0; c < 4; ++c)
        #pragma unroll
        for (int rt = 0; rt < 2; ++rt) acc[c][rt] = (f32x4){0.f, 0.f, 0.f, 0.f};
    layer_mfma(a_hi, a_lo, Wb + (size_t)((r == 2) ? 4 : 3) * 32768, lane, ctbase, acc);
    store_relu_split(acc, b1v, t_hi, t_lo, lane, ctbase);
    __syncthreads();

    f32x4 o[4][2];
    #pragma unroll
    for (int c = 0; c < 4; ++c)
        #pragma unroll
        for (int rt = 0; rt < 2; ++rt) o[c][rt] = (f32x4){0.f, 0.f, 0.f, 0.f};
    layer_mfma(t_hi, t_lo, Wb + (size_t)5 * 32768, lane, ctbase, o);

    #pragma unroll
    for (int c = 0; c < 4; ++c)
        #pragma unroll
        for (int rt = 0; rt < 2; ++rt)
            #pragma unroll
            for (int rr = 0; rr < 4; ++rr) {
                const int row  = rt * 16 + (lane >> 4) * 4 + rr;
                const int node = base + row;
                if (node < N) {
                    const int j = (ctbase + c) * 16 + (lane & 15);
                    out_h[((size_t)node * 3 + r) * D + j] =
                        o[c][rt][rr] + b2v[c] + h[(size_t)node * D + j];
                }
            }
}

// ---------------------------------------------------------------------------
extern "C" void kernel_launch(void* const* d_in, const int* in_sizes, int n_in,
                              void* d_out, int out_size, void* d_ws, size_t ws_size,
                              hipStream_t stream)
{
    const float* h   = (const float*)d_in[0];
    const float* x   = (const float*)d_in[1];
    const int*   ei  = (const int*)d_in[2];
    const float* W1e = (const float*)d_in[3];
    const float* b1e = (const float*)d_in[4];
    const float* W2e = (const float*)d_in[5];
    const float* b2e = (const float*)d_in[6];
    const float* Wg  = (const float*)d_in[7];
    const float* bg  = (const float*)d_in[8];
    const float* W1n = (const float*)d_in[9];
    const float* b1n = (const float*)d_in[10];
    const float* W2n = (const float*)d_in[11];
    const float* b2n = (const float*)d_in[12];

    const int N = in_sizes[0] / D;
    const int E = in_sizes[2] / 2;

    // workspace: R0 | mi1 | Q1b(bf16) | Wb | cnt | off | cur | bucket
    float* R0   = (float*)d_ws;
    float* mi1  = R0 + (size_t)N * D;
    u16*   Q1b  = (u16*)(mi1 + (size_t)N * D);
    short* Wb   = (short*)(Q1b + (size_t)N * D);
    int*   cnt  = (int*)(Wb + 6 * 32768);
    int*   off  = cnt + N;
    int*   cur  = off + N;
    int*   bucket = cur + N;

    float* out_h = (float*)d_out;                 // [N,3,D]
    float* out_x = out_h + (size_t)N * 3 * D;     // [N,3]

    hipMemsetAsync(cnt, 0, (size_t)N * sizeof(int), stream);

    const int ntiles = (N + 31) / 32;
    repack_kernel<<<48, 256, 0, stream>>>(W1e, W2e, W1n, W2n, Wb);
    hist_kernel<<<(E + 255) / 256, 256, 0, stream>>>(ei, E, cnt);
    scan_kernel<<<1, 1024, 0, stream>>>(cnt, off, cur, N);
    fill_kernel<<<(E + 255) / 256, 256, 0, stream>>>(ei, E, cur, bucket);
    node_pre_mfma<<<ntiles * 2, 128, 0, stream>>>(h, Wb, b1e, b2e, Wg, bg, R0, Q1b, N);
    gather_kernel<<<(N + 3) / 4, 256, 0, stream>>>(bucket, off, cnt, Q1b, mi1, N);
    node_mlp_mfma<<<ntiles * 3, 128, 0, stream>>>(h, x, R0, mi1, cnt, Wb, b1n, b2n,
                                                  out_h, out_x, N);
}

// Round 5
// 132.182 us; speedup vs baseline: 4.0913x; 1.1819x over previous
//
#include <hip/hip_runtime.h>

#define D  128
#define SP 136   // LDS activation-plane row stride in shorts (272B: 16B-aligned, 2-way max aliasing)
#define NC 2     // column-tiles per wave (4 waves x 2 ct = 8 ct)

typedef __attribute__((ext_vector_type(8))) short bf16x8;
typedef __attribute__((ext_vector_type(4))) float f32x4;
typedef unsigned short u16;

__device__ __forceinline__ float sigmoidf(float v) { return 1.0f / (1.0f + __expf(-v)); }

__device__ __forceinline__ u16 f2bf(float x) {
    union { float f; unsigned u; } c; c.f = x;
    return (u16)((c.u + 0x7fffu + ((c.u >> 16) & 1u)) >> 16);
}
__device__ __forceinline__ float bf2f(u16 b) {
    union { unsigned u; float f; } c; c.u = ((unsigned)b) << 16; return c.f;
}
__device__ __forceinline__ float bflo(unsigned u) {
    union { unsigned v; float f; } c; c.v = u << 16; return c.f;
}
__device__ __forceinline__ float bfhi(unsigned u) {
    union { unsigned v; float f; } c; c.v = u & 0xffff0000u; return c.f;
}

// ---------------------------------------------------------------------------
// 32x128 @ 128x128 partial layer: this wave computes NC column-tiles
// (ctbase..ctbase+NC-1) for all 32 rows, 3-product hi/lo split.
// A-frag: row = rt*16 + (lane&15), k = ks*32 + (lane>>4)*8 + e  (verified r3)
// ---------------------------------------------------------------------------
__device__ __forceinline__ void layer_mfma(
    const u16* __restrict__ a_hi, const u16* __restrict__ a_lo,
    const short* __restrict__ WbM, int lane, int ctbase, f32x4 acc[NC][2])
{
    #pragma unroll
    for (int ks = 0; ks < 4; ++ks) {
        bf16x8 ah[2], al[2];
        #pragma unroll
        for (int rt = 0; rt < 2; ++rt) {
            const int o = (rt * 16 + (lane & 15)) * SP + ks * 32 + (lane >> 4) * 8;
            ah[rt] = *reinterpret_cast<const bf16x8*>(a_hi + o);
            al[rt] = *reinterpret_cast<const bf16x8*>(a_lo + o);
        }
        #pragma unroll
        for (int c = 0; c < NC; ++c) {
            const short* wp = WbM + ((ctbase + c) * 4 + ks) * 1024 + lane * 8;
            const bf16x8 bh = *reinterpret_cast<const bf16x8*>(wp);
            const bf16x8 bl = *reinterpret_cast<const bf16x8*>(wp + 512);
            #pragma unroll
            for (int rt = 0; rt < 2; ++rt) {
                acc[c][rt] = __builtin_amdgcn_mfma_f32_16x16x32_bf16(ah[rt], bl, acc[c][rt], 0, 0, 0);
                acc[c][rt] = __builtin_amdgcn_mfma_f32_16x16x32_bf16(al[rt], bh, acc[c][rt], 0, 0, 0);
                acc[c][rt] = __builtin_amdgcn_mfma_f32_16x16x32_bf16(ah[rt], bh, acc[c][rt], 0, 0, 0);
            }
        }
    }
}

// relu(acc + b1) -> split hi/lo planes.  C/D: row = rt*16 + (lane>>4)*4 + rr,
// col = ct*16 + (lane&15)  (verified r3)
__device__ __forceinline__ void store_relu_split(
    const f32x4 acc[NC][2], const float b1v[NC],
    u16* __restrict__ t_hi, u16* __restrict__ t_lo, int lane, int ctbase)
{
    #pragma unroll
    for (int c = 0; c < NC; ++c)
        #pragma unroll
        for (int rt = 0; rt < 2; ++rt)
            #pragma unroll
            for (int rr = 0; rr < 4; ++rr) {
                const int row = rt * 16 + (lane >> 4) * 4 + rr;
                const int j   = (ctbase + c) * 16 + (lane & 15);
                const float v = fmaxf(acc[c][rt][rr] + b1v[c], 0.f);
                const u16 hb = f2bf(v);
                t_hi[row * SP + j] = hb;
                t_lo[row * SP + j] = f2bf(v - bf2f(hb));
            }
}

// ---------------------------------------------------------------------------
// Weight repack: 6 fp32 128x128 matrices -> hi/lo bf16 B-fragments (as r3).
// ---------------------------------------------------------------------------
__global__ __launch_bounds__(256) void repack_kernel(
    const float* __restrict__ W1e, const float* __restrict__ W2e,
    const float* __restrict__ W1n, const float* __restrict__ W2n,
    short* __restrict__ Wb)
{
    const int gid = blockIdx.x * 256 + threadIdx.x;
    if (gid >= 6 * 8 * 4 * 64) return;
    const int lane = gid & 63;
    int t = gid >> 6;
    const int ks = t & 3; t >>= 2;
    const int ct = t & 7;
    const int m  = t >> 3;
    const float* src;
    switch (m) {
        case 0: src = W1e;             break;
        case 1: src = W1e + 128 * 128; break;
        case 2: src = W2e;             break;
        case 3: src = W1n;             break;
        case 4: src = W1n + 128 * 128; break;
        default: src = W2n;            break;
    }
    const int j  = ct * 16 + (lane & 15);
    const int k0 = ks * 32 + (lane >> 4) * 8;
    bf16x8 hi, lo;
    #pragma unroll
    for (int e = 0; e < 8; ++e) {
        const float w = src[(size_t)(k0 + e) * 128 + j];
        const u16 hb = f2bf(w);
        hi[e] = (short)hb;
        lo[e] = (short)f2bf(w - bf2f(hb));
    }
    short* dst = Wb + (size_t)m * 32768 + (ct * 4 + ks) * 1024 + lane * 8;
    *reinterpret_cast<bf16x8*>(dst)       = hi;
    *reinterpret_cast<bf16x8*>(dst + 512) = lo;
}

// ---------------------------------------------------------------------------
// Kernel 1: per-node edge-MLP precompute. Block = 256 thr (4 waves), 32 nodes.
// hf split across blocks (grid = 2*ntiles): hf=0 -> R0 fp32, hf=1 -> Q1 bf16.
// LDS activation planes are reused for the t planes (extra barrier).
// ---------------------------------------------------------------------------
__global__ __launch_bounds__(256) void node_pre_mfma(
    const float* __restrict__ h, const short* __restrict__ Wb,
    const float* __restrict__ b1e, const float* __restrict__ b2e,
    const float* __restrict__ Wg,  const float* __restrict__ bg,
    float* __restrict__ R0, u16* __restrict__ Q1b, int N)
{
    __shared__ u16 ab_hi[32 * SP], ab_lo[32 * SP];
    __shared__ float red_s[4][32];

    const int tid  = threadIdx.x, lane = tid & 63, w = tid >> 6;
    const int hf   = blockIdx.x & 1;
    const int base = (blockIdx.x >> 1) * 32;
    const int ctbase = w * NC;

    // stage h, pre-split into hi/lo planes
    for (int idx = tid; idx < 32 * 32; idx += 256) {
        const int row = idx >> 5, c4 = (idx & 31) << 2;
        int node = base + row; if (node >= N) node = N - 1;
        const float4 v = *reinterpret_cast<const float4*>(&h[(size_t)node * D + c4]);
        ushort4 hi, lo;
        hi.x = f2bf(v.x); lo.x = f2bf(v.x - bf2f(hi.x));
        hi.y = f2bf(v.y); lo.y = f2bf(v.y - bf2f(hi.y));
        hi.z = f2bf(v.z); lo.z = f2bf(v.z - bf2f(hi.z));
        hi.w = f2bf(v.w); lo.w = f2bf(v.w - bf2f(hi.w));
        *reinterpret_cast<ushort4*>(&ab_hi[row * SP + c4]) = hi;
        *reinterpret_cast<ushort4*>(&ab_lo[row * SP + c4]) = lo;
    }
    __syncthreads();

    float b1v[NC], b2v[NC], wgv[NC];
    #pragma unroll
    for (int c = 0; c < NC; ++c) {
        const int j = (ctbase + c) * 16 + (lane & 15);
        b1v[c] = b1e[j]; b2v[c] = b2e[j]; wgv[c] = Wg[j];
    }
    const float bgv = bg[0];

    f32x4 acc[NC][2];
    #pragma unroll
    for (int c = 0; c < NC; ++c)
        #pragma unroll
        for (int rt = 0; rt < 2; ++rt) acc[c][rt] = (f32x4){0.f, 0.f, 0.f, 0.f};
    layer_mfma(ab_hi, ab_lo, Wb + (size_t)hf * 32768, lane, ctbase, acc);
    __syncthreads();                               // all waves done reading a
    store_relu_split(acc, b1v, ab_hi, ab_lo, lane, ctbase);   // t over a
    __syncthreads();

    f32x4 p[NC][2];
    #pragma unroll
    for (int c = 0; c < NC; ++c)
        #pragma unroll
        for (int rt = 0; rt < 2; ++rt) p[c][rt] = (f32x4){0.f, 0.f, 0.f, 0.f};
    layer_mfma(ab_hi, ab_lo, Wb + (size_t)2 * 32768, lane, ctbase, p);

    // gate partial over this wave's NC*16 columns, reduced within 16-lane groups
    #pragma unroll
    for (int rt = 0; rt < 2; ++rt)
        #pragma unroll
        for (int rr = 0; rr < 4; ++rr) {
            float part = 0.f;
            #pragma unroll
            for (int c = 0; c < NC; ++c) part += (p[c][rt][rr] + b2v[c]) * wgv[c];
            #pragma unroll
            for (int m = 1; m <= 8; m <<= 1) part += __shfl_xor(part, m, 64);
            if ((lane & 15) == 0)
                red_s[w][rt * 16 + (lane >> 4) * 4 + rr] = part;
        }
    __syncthreads();

    float g[2][4];
    #pragma unroll
    for (int rt = 0; rt < 2; ++rt)
        #pragma unroll
        for (int rr = 0; rr < 4; ++rr) {
            const int row = rt * 16 + (lane >> 4) * 4 + rr;
            g[rt][rr] = sigmoidf(red_s[0][row] + red_s[1][row] +
                                 red_s[2][row] + red_s[3][row] + bgv);
        }

    #pragma unroll
    for (int c = 0; c < NC; ++c)
        #pragma unroll
        for (int rt = 0; rt < 2; ++rt)
            #pragma unroll
            for (int rr = 0; rr < 4; ++rr) {
                const int row  = rt * 16 + (lane >> 4) * 4 + rr;
                const int node = base + row;
                if (node < N) {
                    const int j = (ctbase + c) * 16 + (lane & 15);
                    const float val = (p[c][rt][rr] + b2v[c]) * g[rt][rr];
                    if (hf == 0) R0[(size_t)node * D + j] = val;
                    else         Q1b[(size_t)node * D + j] = f2bf(val);
                }
            }
}

// ---------------------------------------------------------------------------
// CSR build (unchanged)
// ---------------------------------------------------------------------------
__global__ __launch_bounds__(256) void hist_kernel(
    const int* __restrict__ ei, int E, int* __restrict__ cnt)
{
    const int e = blockIdx.x * 256 + threadIdx.x;
    if (e < E) atomicAdd(&cnt[ei[E + e]], 1);
}

__global__ __launch_bounds__(1024) void scan_kernel(
    const int* __restrict__ cnt, int* __restrict__ off, int* __restrict__ cur, int N)
{
    __shared__ int wsum[16];
    const int tid = threadIdx.x, lane = tid & 63, wid = tid >> 6;
    const int IT = (N + 1023) >> 10;   // assumes <= 32
    const int base = tid * IT;
    int v[32];
    int run = 0;
    #pragma unroll
    for (int u = 0; u < 32; ++u) {
        if (u < IT) {
            const int i = base + u;
            run += (i < N) ? cnt[i] : 0;
            v[u] = run;
        }
    }
    const int tot = run;
    int incl = tot;
    #pragma unroll
    for (int o = 1; o < 64; o <<= 1) {
        const int u2 = __shfl_up(incl, o, 64);
        if (lane >= o) incl += u2;
    }
    if (lane == 63) wsum[wid] = incl;
    __syncthreads();
    if (tid < 16) {
        int w = wsum[tid];
        #pragma unroll
        for (int o = 1; o < 16; o <<= 1) {
            const int u2 = __shfl_up(w, o, 16);
            if (tid >= o) w += u2;
        }
        wsum[tid] = w;
    }
    __syncthreads();
    const int tbase = ((wid > 0) ? wsum[wid - 1] : 0) + (incl - tot);
    #pragma unroll
    for (int u = 0; u < 32; ++u) {
        if (u < IT) {
            const int i = base + u;
            if (i < N) {
                const int ex = tbase + ((u > 0) ? v[u - 1] : 0);
                off[i] = ex; cur[i] = ex;
            }
        }
    }
}

__global__ __launch_bounds__(256) void fill_kernel(
    const int* __restrict__ ei, int E, int* __restrict__ cur, int* __restrict__ bucket)
{
    const int e = blockIdx.x * 256 + threadIdx.x;
    if (e < E) {
        const int pos = atomicAdd(&cur[ei[E + e]], 1);
        bucket[pos] = ei[e];
    }
}

// ---------------------------------------------------------------------------
// Gather: mi1[n] = sum_{dst==n} Q1[src] (bf16 source). One wave per node,
// 4 edge slots x 16 lanes; 2 edges in flight per slot.
// ---------------------------------------------------------------------------
__global__ __launch_bounds__(256) void gather_kernel(
    const int* __restrict__ bucket, const int* __restrict__ off,
    const int* __restrict__ cntv, const u16* __restrict__ Q1b,
    float* __restrict__ mi1, int N)
{
    const int n = blockIdx.x * 4 + (threadIdx.x >> 6);
    if (n >= N) return;
    const int lane = threadIdx.x & 63;
    const int slot = lane >> 4, c16 = lane & 15;
    const int beg = off[n], deg = cntv[n];
    const u16* __restrict__ Qc = Q1b + c16 * 8;
    float a[8] = {0.f, 0.f, 0.f, 0.f, 0.f, 0.f, 0.f, 0.f};
    int i = slot;
    for (; i + 4 < deg; i += 8) {
        const int s0 = bucket[beg + i];
        const int s1 = bucket[beg + i + 4];
        const uint4 q0 = *reinterpret_cast<const uint4*>(Qc + (size_t)s0 * D);
        const uint4 q1 = *reinterpret_cast<const uint4*>(Qc + (size_t)s1 * D);
        a[0] += bflo(q0.x); a[1] += bfhi(q0.x);
        a[2] += bflo(q0.y); a[3] += bfhi(q0.y);
        a[4] += bflo(q0.z); a[5] += bfhi(q0.z);
        a[6] += bflo(q0.w); a[7] += bfhi(q0.w);
        a[0] += bflo(q1.x); a[1] += bfhi(q1.x);
        a[2] += bflo(q1.y); a[3] += bfhi(q1.y);
        a[4] += bflo(q1.z); a[5] += bfhi(q1.z);
        a[6] += bflo(q1.w); a[7] += bfhi(q1.w);
    }
    if (i < deg) {
        const int s = bucket[beg + i];
        const uint4 q = *reinterpret_cast<const uint4*>(Qc + (size_t)s * D);
        a[0] += bflo(q.x); a[1] += bfhi(q.x);
        a[2] += bflo(q.y); a[3] += bfhi(q.y);
        a[4] += bflo(q.z); a[5] += bfhi(q.z);
        a[6] += bflo(q.w); a[7] += bfhi(q.w);
    }
    #pragma unroll
    for (int e = 0; e < 8; ++e) {
        a[e] += __shfl_xor(a[e], 16, 64);
        a[e] += __shfl_xor(a[e], 32, 64);
    }
    if (slot == 0) {
        const float4 v0 = {a[0], a[1], a[2], a[3]};
        const float4 v1 = {a[4], a[5], a[6], a[7]};
        *reinterpret_cast<float4*>(&mi1[(size_t)n * D + c16 * 8])     = v0;
        *reinterpret_cast<float4*>(&mi1[(size_t)n * D + c16 * 8 + 4]) = v1;
    }
}

// ---------------------------------------------------------------------------
// Kernel 3: node MLP + residual. Block = 256 thr (4 waves), 32 nodes, one r.
// grid = 3*ntiles: r = blockIdx.x % 3.  row0: cnt*R0, row1: mi1, row2: h.
// ---------------------------------------------------------------------------
__global__ __launch_bounds__(256) void node_mlp_mfma(
    const float* __restrict__ h,  const float* __restrict__ x,
    const float* __restrict__ R0, const float* __restrict__ mi1,
    const int* __restrict__ cnt,  const short* __restrict__ Wb,
    const float* __restrict__ b1n, const float* __restrict__ b2n,
    float* __restrict__ out_h, float* __restrict__ out_x, int N)
{
    __shared__ u16 ab_hi[32 * SP], ab_lo[32 * SP];

    const int tid  = threadIdx.x, lane = tid & 63, w = tid >> 6;
    const int r    = blockIdx.x % 3;
    const int tile = blockIdx.x / 3;
    const int base = tile * 32;
    const int ctbase = w * NC;

    if (r == 0) {   // x passthrough once per tile
        const int xi = tile * 96 + tid;
        if (tid < 96 && xi < N * 3) out_x[xi] = x[xi];
    }

    const float* __restrict__ src = (r == 0) ? R0 : (r == 1) ? mi1 : h;
    for (int idx = tid; idx < 32 * 32; idx += 256) {
        const int row = idx >> 5, c4 = (idx & 31) << 2;
        int node = base + row; if (node >= N) node = N - 1;
        float4 v = *reinterpret_cast<const float4*>(&src[(size_t)node * D + c4]);
        if (r == 0) {
            const float cv = (float)cnt[node];
            v.x *= cv; v.y *= cv; v.z *= cv; v.w *= cv;
        }
        ushort4 hi, lo;
        hi.x = f2bf(v.x); lo.x = f2bf(v.x - bf2f(hi.x));
        hi.y = f2bf(v.y); lo.y = f2bf(v.y - bf2f(hi.y));
        hi.z = f2bf(v.z); lo.z = f2bf(v.z - bf2f(hi.z));
        hi.w = f2bf(v.w); lo.w = f2bf(v.w - bf2f(hi.w));
        *reinterpret_cast<ushort4*>(&ab_hi[row * SP + c4]) = hi;
        *reinterpret_cast<ushort4*>(&ab_lo[row * SP + c4]) = lo;
    }
    __syncthreads();

    float b1v[NC], b2v[NC];
    #pragma unroll
    for (int c = 0; c < NC; ++c) {
        const int j = (ctbase + c) * 16 + (lane & 15);
        b1v[c] = b1n[j]; b2v[c] = b2n[j];
    }

    f32x4 acc[NC][2];
    #pragma unroll
    for (int c = 0; c < NC; ++c)
        #pragma unroll
        for (int rt = 0; rt < 2; ++rt) acc[c][rt] = (f32x4){0.f, 0.f, 0.f, 0.f};
    layer_mfma(ab_hi, ab_lo, Wb + (size_t)((r == 2) ? 4 : 3) * 32768, lane, ctbase, acc);
    __syncthreads();                               // all waves done reading a
    store_relu_split(acc, b1v, ab_hi, ab_lo, lane, ctbase);   // t over a
    __syncthreads();

    f32x4 o[NC][2];
    #pragma unroll
    for (int c = 0; c < NC; ++c)
        #pragma unroll
        for (int rt = 0; rt < 2; ++rt) o[c][rt] = (f32x4){0.f, 0.f, 0.f, 0.f};
    layer_mfma(ab_hi, ab_lo, Wb + (size_t)5 * 32768, lane, ctbase, o);

    #pragma unroll
    for (int c = 0; c < NC; ++c)
        #pragma unroll
        for (int rt = 0; rt < 2; ++rt)
            #pragma unroll
            for (int rr = 0; rr < 4; ++rr) {
                const int row  = rt * 16 + (lane >> 4) * 4 + rr;
                const int node = base + row;
                if (node < N) {
                    const int j = (ctbase + c) * 16 + (lane & 15);
                    out_h[((size_t)node * 3 + r) * D + j] =
                        o[c][rt][rr] + b2v[c] + h[(size_t)node * D + j];
                }
            }
}

// ---------------------------------------------------------------------------
extern "C" void kernel_launch(void* const* d_in, const int* in_sizes, int n_in,
                              void* d_out, int out_size, void* d_ws, size_t ws_size,
                              hipStream_t stream)
{
    const float* h   = (const float*)d_in[0];
    const float* x   = (const float*)d_in[1];
    const int*   ei  = (const int*)d_in[2];
    const float* W1e = (const float*)d_in[3];
    const float* b1e = (const float*)d_in[4];
    const float* W2e = (const float*)d_in[5];
    const float* b2e = (const float*)d_in[6];
    const float* Wg  = (const float*)d_in[7];
    const float* bg  = (const float*)d_in[8];
    const float* W1n = (const float*)d_in[9];
    const float* b1n = (const float*)d_in[10];
    const float* W2n = (const float*)d_in[11];
    const float* b2n = (const float*)d_in[12];

    const int N = in_sizes[0] / D;
    const int E = in_sizes[2] / 2;

    // workspace: R0 | mi1 | Q1b(bf16) | Wb | cnt | off | cur | bucket
    float* R0   = (float*)d_ws;
    float* mi1  = R0 + (size_t)N * D;
    u16*   Q1b  = (u16*)(mi1 + (size_t)N * D);
    short* Wb   = (short*)(Q1b + (size_t)N * D);
    int*   cnt  = (int*)(Wb + 6 * 32768);
    int*   off  = cnt + N;
    int*   cur  = off + N;
    int*   bucket = cur + N;

    float* out_h = (float*)d_out;                 // [N,3,D]
    float* out_x = out_h + (size_t)N * 3 * D;     // [N,3]

    hipMemsetAsync(cnt, 0, (size_t)N * sizeof(int), stream);

    const int ntiles = (N + 31) / 32;
    repack_kernel<<<48, 256, 0, stream>>>(W1e, W2e, W1n, W2n, Wb);
    hist_kernel<<<(E + 255) / 256, 256, 0, stream>>>(ei, E, cnt);
    scan_kernel<<<1, 1024, 0, stream>>>(cnt, off, cur, N);
    fill_kernel<<<(E + 255) / 256, 256, 0, stream>>>(ei, E, cur, bucket);
    node_pre_mfma<<<ntiles * 2, 256, 0, stream>>>(h, Wb, b1e, b2e, Wg, bg, R0, Q1b, N);
    gather_kernel<<<(N + 3) / 4, 256, 0, stream>>>(bucket, off, cnt, Q1b, mi1, N);
    node_mlp_mfma<<<ntiles * 3, 256, 0, stream>>>(h, x, R0, mi1, cnt, Wb, b1n, b2n,
                                                  out_h, out_x, N);
}

// Round 6
// 126.655 us; speedup vs baseline: 4.2698x; 1.0436x over previous
//
#include <hip/hip_runtime.h>

#define D  128
#define SP 136   // LDS activation-plane row stride in shorts (272B: 16B-aligned, 2-way max aliasing)
#define NC 2     // column-tiles per wave (4 waves x 2 ct = 8 ct)

typedef __attribute__((ext_vector_type(8))) short bf16x8;
typedef __attribute__((ext_vector_type(4))) float f32x4;
typedef unsigned short u16;

__device__ __forceinline__ float sigmoidf(float v) { return 1.0f / (1.0f + __expf(-v)); }

__device__ __forceinline__ u16 f2bf(float x) {
    union { float f; unsigned u; } c; c.f = x;
    return (u16)((c.u + 0x7fffu + ((c.u >> 16) & 1u)) >> 16);
}
__device__ __forceinline__ float bf2f(u16 b) {
    union { unsigned u; float f; } c; c.u = ((unsigned)b) << 16; return c.f;
}
__device__ __forceinline__ float bflo(unsigned u) {
    union { unsigned v; float f; } c; c.v = u << 16; return c.f;
}
__device__ __forceinline__ float bfhi(unsigned u) {
    union { unsigned v; float f; } c; c.v = u & 0xffff0000u; return c.f;
}

// ---------------------------------------------------------------------------
// 32x128 @ 128x128 partial layer: this wave computes NC column-tiles
// (ctbase..ctbase+NC-1) for all 32 rows, 3-product hi/lo split.
// A-frag: row = rt*16 + (lane&15), k = ks*32 + (lane>>4)*8 + e  (verified r3)
// ---------------------------------------------------------------------------
__device__ __forceinline__ void layer_mfma(
    const u16* __restrict__ a_hi, const u16* __restrict__ a_lo,
    const short* __restrict__ WbM, int lane, int ctbase, f32x4 acc[NC][2])
{
    #pragma unroll
    for (int ks = 0; ks < 4; ++ks) {
        bf16x8 ah[2], al[2];
        #pragma unroll
        for (int rt = 0; rt < 2; ++rt) {
            const int o = (rt * 16 + (lane & 15)) * SP + ks * 32 + (lane >> 4) * 8;
            ah[rt] = *reinterpret_cast<const bf16x8*>(a_hi + o);
            al[rt] = *reinterpret_cast<const bf16x8*>(a_lo + o);
        }
        #pragma unroll
        for (int c = 0; c < NC; ++c) {
            const short* wp = WbM + ((ctbase + c) * 4 + ks) * 1024 + lane * 8;
            const bf16x8 bh = *reinterpret_cast<const bf16x8*>(wp);
            const bf16x8 bl = *reinterpret_cast<const bf16x8*>(wp + 512);
            #pragma unroll
            for (int rt = 0; rt < 2; ++rt) {
                acc[c][rt] = __builtin_amdgcn_mfma_f32_16x16x32_bf16(ah[rt], bl, acc[c][rt], 0, 0, 0);
                acc[c][rt] = __builtin_amdgcn_mfma_f32_16x16x32_bf16(al[rt], bh, acc[c][rt], 0, 0, 0);
                acc[c][rt] = __builtin_amdgcn_mfma_f32_16x16x32_bf16(ah[rt], bh, acc[c][rt], 0, 0, 0);
            }
        }
    }
}

// relu(acc + b1) -> split hi/lo planes.  C/D: row = rt*16 + (lane>>4)*4 + rr,
// col = ct*16 + (lane&15)  (verified r3)
__device__ __forceinline__ void store_relu_split(
    const f32x4 acc[NC][2], const float b1v[NC],
    u16* __restrict__ t_hi, u16* __restrict__ t_lo, int lane, int ctbase)
{
    #pragma unroll
    for (int c = 0; c < NC; ++c)
        #pragma unroll
        for (int rt = 0; rt < 2; ++rt)
            #pragma unroll
            for (int rr = 0; rr < 4; ++rr) {
                const int row = rt * 16 + (lane >> 4) * 4 + rr;
                const int j   = (ctbase + c) * 16 + (lane & 15);
                const float v = fmaxf(acc[c][rt][rr] + b1v[c], 0.f);
                const u16 hb = f2bf(v);
                t_hi[row * SP + j] = hb;
                t_lo[row * SP + j] = f2bf(v - bf2f(hb));
            }
}

// ---------------------------------------------------------------------------
// Fused: zero cnt (first ZB blocks) || weight repack (next 48 blocks).
// Repack: 6 fp32 128x128 matrices -> hi/lo bf16 B-fragments (as r3).
// ---------------------------------------------------------------------------
__global__ __launch_bounds__(256) void zero_repack_kernel(
    int* __restrict__ cnt, int N, int ZB,
    const float* __restrict__ W1e, const float* __restrict__ W2e,
    const float* __restrict__ W1n, const float* __restrict__ W2n,
    short* __restrict__ Wb)
{
    if (blockIdx.x < (unsigned)ZB) {
        const int i = blockIdx.x * 256 + threadIdx.x;
        if (i < N) cnt[i] = 0;
        return;
    }
    const int gid = (blockIdx.x - ZB) * 256 + threadIdx.x;
    if (gid >= 6 * 8 * 4 * 64) return;
    const int lane = gid & 63;
    int t = gid >> 6;
    const int ks = t & 3; t >>= 2;
    const int ct = t & 7;
    const int m  = t >> 3;
    const float* src;
    switch (m) {
        case 0: src = W1e;             break;
        case 1: src = W1e + 128 * 128; break;
        case 2: src = W2e;             break;
        case 3: src = W1n;             break;
        case 4: src = W1n + 128 * 128; break;
        default: src = W2n;            break;
    }
    const int j  = ct * 16 + (lane & 15);
    const int k0 = ks * 32 + (lane >> 4) * 8;
    bf16x8 hi, lo;
    #pragma unroll
    for (int e = 0; e < 8; ++e) {
        const float w = src[(size_t)(k0 + e) * 128 + j];
        const u16 hb = f2bf(w);
        hi[e] = (short)hb;
        lo[e] = (short)f2bf(w - bf2f(hb));
    }
    short* dst = Wb + (size_t)m * 32768 + (ct * 4 + ks) * 1024 + lane * 8;
    *reinterpret_cast<bf16x8*>(dst)       = hi;
    *reinterpret_cast<bf16x8*>(dst + 512) = lo;
}

// ---------------------------------------------------------------------------
// CSR histogram + single-block scan
// ---------------------------------------------------------------------------
__global__ __launch_bounds__(256) void hist_kernel(
    const int* __restrict__ ei, int E, int* __restrict__ cnt)
{
    const int e = blockIdx.x * 256 + threadIdx.x;
    if (e < E) atomicAdd(&cnt[ei[E + e]], 1);
}

__global__ __launch_bounds__(1024) void scan_kernel(
    const int* __restrict__ cnt, int* __restrict__ off, int* __restrict__ cur, int N)
{
    __shared__ int wsum[16];
    const int tid = threadIdx.x, lane = tid & 63, wid = tid >> 6;
    const int IT = (N + 1023) >> 10;   // assumes <= 32
    const int base = tid * IT;
    int v[32];
    int run = 0;
    #pragma unroll
    for (int u = 0; u < 32; ++u) {
        if (u < IT) {
            const int i = base + u;
            run += (i < N) ? cnt[i] : 0;
            v[u] = run;
        }
    }
    const int tot = run;
    int incl = tot;
    #pragma unroll
    for (int o = 1; o < 64; o <<= 1) {
        const int u2 = __shfl_up(incl, o, 64);
        if (lane >= o) incl += u2;
    }
    if (lane == 63) wsum[wid] = incl;
    __syncthreads();
    if (tid < 16) {
        int w = wsum[tid];
        #pragma unroll
        for (int o = 1; o < 16; o <<= 1) {
            const int u2 = __shfl_up(w, o, 16);
            if (tid >= o) w += u2;
        }
        wsum[tid] = w;
    }
    __syncthreads();
    const int tbase = ((wid > 0) ? wsum[wid - 1] : 0) + (incl - tot);
    #pragma unroll
    for (int u = 0; u < 32; ++u) {
        if (u < IT) {
            const int i = base + u;
            if (i < N) {
                const int ex = tbase + ((u > 0) ? v[u - 1] : 0);
                off[i] = ex; cur[i] = ex;
            }
        }
    }
}

// ---------------------------------------------------------------------------
// Fused: node_pre (first PB blocks) || CSR bucket fill (next FB blocks).
// node_pre: per-node edge-MLP. Block = 256 thr (4 waves), 32 nodes.
// hf split across blocks: hf=0 -> R0 fp32, hf=1 -> Q1 bf16.
// ---------------------------------------------------------------------------
__global__ __launch_bounds__(256) void pre_fill_kernel(
    const float* __restrict__ h, const short* __restrict__ Wb,
    const float* __restrict__ b1e, const float* __restrict__ b2e,
    const float* __restrict__ Wg,  const float* __restrict__ bg,
    float* __restrict__ R0, u16* __restrict__ Q1b, int N, int PB,
    const int* __restrict__ ei, int E, int* __restrict__ cur, int* __restrict__ bucket)
{
    __shared__ u16 ab_hi[32 * SP], ab_lo[32 * SP];
    __shared__ float red_s[4][32];

    if (blockIdx.x >= (unsigned)PB) {   // ---- fill path ----
        const int e = (blockIdx.x - PB) * 256 + threadIdx.x;
        if (e < E) {
            const int pos = atomicAdd(&cur[ei[E + e]], 1);
            bucket[pos] = ei[e];
        }
        return;
    }

    // ---- node_pre path ----
    const int tid  = threadIdx.x, lane = tid & 63, w = tid >> 6;
    const int hf   = blockIdx.x & 1;
    const int base = (blockIdx.x >> 1) * 32;
    const int ctbase = w * NC;

    // stage h, pre-split into hi/lo planes
    for (int idx = tid; idx < 32 * 32; idx += 256) {
        const int row = idx >> 5, c4 = (idx & 31) << 2;
        int node = base + row; if (node >= N) node = N - 1;
        const float4 v = *reinterpret_cast<const float4*>(&h[(size_t)node * D + c4]);
        ushort4 hi, lo;
        hi.x = f2bf(v.x); lo.x = f2bf(v.x - bf2f(hi.x));
        hi.y = f2bf(v.y); lo.y = f2bf(v.y - bf2f(hi.y));
        hi.z = f2bf(v.z); lo.z = f2bf(v.z - bf2f(hi.z));
        hi.w = f2bf(v.w); lo.w = f2bf(v.w - bf2f(hi.w));
        *reinterpret_cast<ushort4*>(&ab_hi[row * SP + c4]) = hi;
        *reinterpret_cast<ushort4*>(&ab_lo[row * SP + c4]) = lo;
    }
    __syncthreads();

    float b1v[NC], b2v[NC], wgv[NC];
    #pragma unroll
    for (int c = 0; c < NC; ++c) {
        const int j = (ctbase + c) * 16 + (lane & 15);
        b1v[c] = b1e[j]; b2v[c] = b2e[j]; wgv[c] = Wg[j];
    }
    const float bgv = bg[0];

    f32x4 acc[NC][2];
    #pragma unroll
    for (int c = 0; c < NC; ++c)
        #pragma unroll
        for (int rt = 0; rt < 2; ++rt) acc[c][rt] = (f32x4){0.f, 0.f, 0.f, 0.f};
    layer_mfma(ab_hi, ab_lo, Wb + (size_t)hf * 32768, lane, ctbase, acc);
    __syncthreads();                               // all waves done reading a
    store_relu_split(acc, b1v, ab_hi, ab_lo, lane, ctbase);   // t over a
    __syncthreads();

    f32x4 p[NC][2];
    #pragma unroll
    for (int c = 0; c < NC; ++c)
        #pragma unroll
        for (int rt = 0; rt < 2; ++rt) p[c][rt] = (f32x4){0.f, 0.f, 0.f, 0.f};
    layer_mfma(ab_hi, ab_lo, Wb + (size_t)2 * 32768, lane, ctbase, p);

    // gate partial over this wave's NC*16 columns, reduced within 16-lane groups
    #pragma unroll
    for (int rt = 0; rt < 2; ++rt)
        #pragma unroll
        for (int rr = 0; rr < 4; ++rr) {
            float part = 0.f;
            #pragma unroll
            for (int c = 0; c < NC; ++c) part += (p[c][rt][rr] + b2v[c]) * wgv[c];
            #pragma unroll
            for (int m = 1; m <= 8; m <<= 1) part += __shfl_xor(part, m, 64);
            if ((lane & 15) == 0)
                red_s[w][rt * 16 + (lane >> 4) * 4 + rr] = part;
        }
    __syncthreads();

    float g[2][4];
    #pragma unroll
    for (int rt = 0; rt < 2; ++rt)
        #pragma unroll
        for (int rr = 0; rr < 4; ++rr) {
            const int row = rt * 16 + (lane >> 4) * 4 + rr;
            g[rt][rr] = sigmoidf(red_s[0][row] + red_s[1][row] +
                                 red_s[2][row] + red_s[3][row] + bgv);
        }

    #pragma unroll
    for (int c = 0; c < NC; ++c)
        #pragma unroll
        for (int rt = 0; rt < 2; ++rt)
            #pragma unroll
            for (int rr = 0; rr < 4; ++rr) {
                const int row  = rt * 16 + (lane >> 4) * 4 + rr;
                const int node = base + row;
                if (node < N) {
                    const int j = (ctbase + c) * 16 + (lane & 15);
                    const float val = (p[c][rt][rr] + b2v[c]) * g[rt][rr];
                    if (hf == 0) R0[(size_t)node * D + j] = val;
                    else         Q1b[(size_t)node * D + j] = f2bf(val);
                }
            }
}

// ---------------------------------------------------------------------------
// Gather: mi1[n] = sum_{dst==n} Q1[src] (bf16 source). One wave per node,
// 4 edge slots x 16 lanes; 2 edges in flight per slot.
// ---------------------------------------------------------------------------
__global__ __launch_bounds__(256) void gather_kernel(
    const int* __restrict__ bucket, const int* __restrict__ off,
    const int* __restrict__ cntv, const u16* __restrict__ Q1b,
    float* __restrict__ mi1, int N)
{
    const int n = blockIdx.x * 4 + (threadIdx.x >> 6);
    if (n >= N) return;
    const int lane = threadIdx.x & 63;
    const int slot = lane >> 4, c16 = lane & 15;
    const int beg = off[n], deg = cntv[n];
    const u16* __restrict__ Qc = Q1b + c16 * 8;
    float a[8] = {0.f, 0.f, 0.f, 0.f, 0.f, 0.f, 0.f, 0.f};
    int i = slot;
    for (; i + 4 < deg; i += 8) {
        const int s0 = bucket[beg + i];
        const int s1 = bucket[beg + i + 4];
        const uint4 q0 = *reinterpret_cast<const uint4*>(Qc + (size_t)s0 * D);
        const uint4 q1 = *reinterpret_cast<const uint4*>(Qc + (size_t)s1 * D);
        a[0] += bflo(q0.x); a[1] += bfhi(q0.x);
        a[2] += bflo(q0.y); a[3] += bfhi(q0.y);
        a[4] += bflo(q0.z); a[5] += bfhi(q0.z);
        a[6] += bflo(q0.w); a[7] += bfhi(q0.w);
        a[0] += bflo(q1.x); a[1] += bfhi(q1.x);
        a[2] += bflo(q1.y); a[3] += bfhi(q1.y);
        a[4] += bflo(q1.z); a[5] += bfhi(q1.z);
        a[6] += bflo(q1.w); a[7] += bfhi(q1.w);
    }
    if (i < deg) {
        const int s = bucket[beg + i];
        const uint4 q = *reinterpret_cast<const uint4*>(Qc + (size_t)s * D);
        a[0] += bflo(q.x); a[1] += bfhi(q.x);
        a[2] += bflo(q.y); a[3] += bfhi(q.y);
        a[4] += bflo(q.z); a[5] += bfhi(q.z);
        a[6] += bflo(q.w); a[7] += bfhi(q.w);
    }
    #pragma unroll
    for (int e = 0; e < 8; ++e) {
        a[e] += __shfl_xor(a[e], 16, 64);
        a[e] += __shfl_xor(a[e], 32, 64);
    }
    if (slot == 0) {
        const float4 v0 = {a[0], a[1], a[2], a[3]};
        const float4 v1 = {a[4], a[5], a[6], a[7]};
        *reinterpret_cast<float4*>(&mi1[(size_t)n * D + c16 * 8])     = v0;
        *reinterpret_cast<float4*>(&mi1[(size_t)n * D + c16 * 8 + 4]) = v1;
    }
}

// ---------------------------------------------------------------------------
// Kernel 3: node MLP + residual. Block = 256 thr (4 waves), 32 nodes, one r.
// grid = 3*ntiles: r = blockIdx.x % 3.  row0: cnt*R0, row1: mi1, row2: h.
// ---------------------------------------------------------------------------
__global__ __launch_bounds__(256) void node_mlp_mfma(
    const float* __restrict__ h,  const float* __restrict__ x,
    const float* __restrict__ R0, const float* __restrict__ mi1,
    const int* __restrict__ cnt,  const short* __restrict__ Wb,
    const float* __restrict__ b1n, const float* __restrict__ b2n,
    float* __restrict__ out_h, float* __restrict__ out_x, int N)
{
    __shared__ u16 ab_hi[32 * SP], ab_lo[32 * SP];

    const int tid  = threadIdx.x, lane = tid & 63, w = tid >> 6;
    const int r    = blockIdx.x % 3;
    const int tile = blockIdx.x / 3;
    const int base = tile * 32;
    const int ctbase = w * NC;

    if (r == 0) {   // x passthrough once per tile
        const int xi = tile * 96 + tid;
        if (tid < 96 && xi < N * 3) out_x[xi] = x[xi];
    }

    const float* __restrict__ src = (r == 0) ? R0 : (r == 1) ? mi1 : h;
    for (int idx = tid; idx < 32 * 32; idx += 256) {
        const int row = idx >> 5, c4 = (idx & 31) << 2;
        int node = base + row; if (node >= N) node = N - 1;
        float4 v = *reinterpret_cast<const float4*>(&src[(size_t)node * D + c4]);
        if (r == 0) {
            const float cv = (float)cnt[node];
            v.x *= cv; v.y *= cv; v.z *= cv; v.w *= cv;
        }
        ushort4 hi, lo;
        hi.x = f2bf(v.x); lo.x = f2bf(v.x - bf2f(hi.x));
        hi.y = f2bf(v.y); lo.y = f2bf(v.y - bf2f(hi.y));
        hi.z = f2bf(v.z); lo.z = f2bf(v.z - bf2f(hi.z));
        hi.w = f2bf(v.w); lo.w = f2bf(v.w - bf2f(hi.w));
        *reinterpret_cast<ushort4*>(&ab_hi[row * SP + c4]) = hi;
        *reinterpret_cast<ushort4*>(&ab_lo[row * SP + c4]) = lo;
    }
    __syncthreads();

    float b1v[NC], b2v[NC];
    #pragma unroll
    for (int c = 0; c < NC; ++c) {
        const int j = (ctbase + c) * 16 + (lane & 15);
        b1v[c] = b1n[j]; b2v[c] = b2n[j];
    }

    f32x4 acc[NC][2];
    #pragma unroll
    for (int c = 0; c < NC; ++c)
        #pragma unroll
        for (int rt = 0; rt < 2; ++rt) acc[c][rt] = (f32x4){0.f, 0.f, 0.f, 0.f};
    layer_mfma(ab_hi, ab_lo, Wb + (size_t)((r == 2) ? 4 : 3) * 32768, lane, ctbase, acc);
    __syncthreads();                               // all waves done reading a
    store_relu_split(acc, b1v, ab_hi, ab_lo, lane, ctbase);   // t over a
    __syncthreads();

    f32x4 o[NC][2];
    #pragma unroll
    for (int c = 0; c < NC; ++c)
        #pragma unroll
        for (int rt = 0; rt < 2; ++rt) o[c][rt] = (f32x4){0.f, 0.f, 0.f, 0.f};
    layer_mfma(ab_hi, ab_lo, Wb + (size_t)5 * 32768, lane, ctbase, o);

    #pragma unroll
    for (int c = 0; c < NC; ++c)
        #pragma unroll
        for (int rt = 0; rt < 2; ++rt)
            #pragma unroll
            for (int rr = 0; rr < 4; ++rr) {
                const int row  = rt * 16 + (lane >> 4) * 4 + rr;
                const int node = base + row;
                if (node < N) {
                    const int j = (ctbase + c) * 16 + (lane & 15);
                    out_h[((size_t)node * 3 + r) * D + j] =
                        o[c][rt][rr] + b2v[c] + h[(size_t)node * D + j];
                }
            }
}

// ---------------------------------------------------------------------------
extern "C" void kernel_launch(void* const* d_in, const int* in_sizes, int n_in,
                              void* d_out, int out_size, void* d_ws, size_t ws_size,
                              hipStream_t stream)
{
    const float* h   = (const float*)d_in[0];
    const float* x   = (const float*)d_in[1];
    const int*   ei  = (const int*)d_in[2];
    const float* W1e = (const float*)d_in[3];
    const float* b1e = (const float*)d_in[4];
    const float* W2e = (const float*)d_in[5];
    const float* b2e = (const float*)d_in[6];
    const float* Wg  = (const float*)d_in[7];
    const float* bg  = (const float*)d_in[8];
    const float* W1n = (const float*)d_in[9];
    const float* b1n = (const float*)d_in[10];
    const float* W2n = (const float*)d_in[11];
    const float* b2n = (const float*)d_in[12];

    const int N = in_sizes[0] / D;
    const int E = in_sizes[2] / 2;

    // workspace: R0 | mi1 | Q1b(bf16) | Wb | cnt | off | cur | bucket
    float* R0   = (float*)d_ws;
    float* mi1  = R0 + (size_t)N * D;
    u16*   Q1b  = (u16*)(mi1 + (size_t)N * D);
    short* Wb   = (short*)(Q1b + (size_t)N * D);
    int*   cnt  = (int*)(Wb + 6 * 32768);
    int*   off  = cnt + N;
    int*   cur  = off + N;
    int*   bucket = cur + N;

    float* out_h = (float*)d_out;                 // [N,3,D]
    float* out_x = out_h + (size_t)N * 3 * D;     // [N,3]

    const int ntiles = (N + 31) / 32;
    const int ZB = (N + 255) / 256;               // zero blocks
    const int RB = 48;                            // repack blocks
    const int PB = ntiles * 2;                    // node_pre blocks
    const int FB = (E + 255) / 256;               // fill blocks

    zero_repack_kernel<<<ZB + RB, 256, 0, stream>>>(cnt, N, ZB, W1e, W2e, W1n, W2n, Wb);
    hist_kernel<<<(E + 255) / 256, 256, 0, stream>>>(ei, E, cnt);
    scan_kernel<<<1, 1024, 0, stream>>>(cnt, off, cur, N);
    pre_fill_kernel<<<PB + FB, 256, 0, stream>>>(h, Wb, b1e, b2e, Wg, bg, R0, Q1b, N, PB,
                                                 ei, E, cur, bucket);
    gather_kernel<<<(N + 3) / 4, 256, 0, stream>>>(bucket, off, cnt, Q1b, mi1, N);
    node_mlp_mfma<<<ntiles * 3, 256, 0, stream>>>(h, x, R0, mi1, cnt, Wb, b1n, b2n,
                                                  out_h, out_x, N);
}

// Round 7
// 113.135 us; speedup vs baseline: 4.7801x; 1.1195x over previous
//
#include <hip/hip_runtime.h>

#define D  128
#define SP 136   // u16 row stride for hi/lo LDS planes (272B, 16B-aligned)
#define FS 132   // fp32 row stride for LDS output staging (528B, 16B-aligned)
#define NC 2     // column-tiles per wave (4 waves x 2 ct = 8 ct)

typedef __attribute__((ext_vector_type(8))) short bf16x8;
typedef __attribute__((ext_vector_type(4))) float f32x4;
typedef unsigned short u16;

__device__ __forceinline__ float sigmoidf(float v) { return 1.0f / (1.0f + __expf(-v)); }

__device__ __forceinline__ u16 f2bf(float x) {
    union { float f; unsigned u; } c; c.f = x;
    return (u16)((c.u + 0x7fffu + ((c.u >> 16) & 1u)) >> 16);
}
__device__ __forceinline__ float bf2f(u16 b) {
    union { unsigned u; float f; } c; c.u = ((unsigned)b) << 16; return c.f;
}
__device__ __forceinline__ float bflo(unsigned u) {
    union { unsigned v; float f; } c; c.v = u << 16; return c.f;
}
__device__ __forceinline__ float bfhi(unsigned u) {
    union { unsigned v; float f; } c; c.v = u & 0xffff0000u; return c.f;
}

// ---------------------------------------------------------------------------
// 32x128 @ 128x128 partial layer, 2-product split: A = Ah+Al (exact),
// B = Bh (bf16-rounded weights).  acc += Al*Bh + Ah*Bh.
// A-frag: row = rt*16 + (lane&15), k = ks*32 + (lane>>4)*8 + e  (verified r3)
// ---------------------------------------------------------------------------
__device__ __forceinline__ void layer_mfma(
    const u16* __restrict__ a_hi, const u16* __restrict__ a_lo,
    const short* __restrict__ WbM, int lane, int ctbase, f32x4 acc[NC][2])
{
    #pragma unroll
    for (int ks = 0; ks < 4; ++ks) {
        bf16x8 ah[2], al[2];
        #pragma unroll
        for (int rt = 0; rt < 2; ++rt) {
            const int o = (rt * 16 + (lane & 15)) * SP + ks * 32 + (lane >> 4) * 8;
            ah[rt] = *reinterpret_cast<const bf16x8*>(a_hi + o);
            al[rt] = *reinterpret_cast<const bf16x8*>(a_lo + o);
        }
        #pragma unroll
        for (int c = 0; c < NC; ++c) {
            const short* wp = WbM + ((ctbase + c) * 4 + ks) * 1024 + lane * 8;
            const bf16x8 bh = *reinterpret_cast<const bf16x8*>(wp);
            #pragma unroll
            for (int rt = 0; rt < 2; ++rt) {
                acc[c][rt] = __builtin_amdgcn_mfma_f32_16x16x32_bf16(al[rt], bh, acc[c][rt], 0, 0, 0);
                acc[c][rt] = __builtin_amdgcn_mfma_f32_16x16x32_bf16(ah[rt], bh, acc[c][rt], 0, 0, 0);
            }
        }
    }
}

// relu(acc + b1) -> split hi/lo planes.  C/D: row = rt*16 + (lane>>4)*4 + rr,
// col = ct*16 + (lane&15)  (verified r3)
__device__ __forceinline__ void store_relu_split(
    const f32x4 acc[NC][2], const float b1v[NC],
    u16* __restrict__ t_hi, u16* __restrict__ t_lo, int lane, int ctbase)
{
    #pragma unroll
    for (int c = 0; c < NC; ++c)
        #pragma unroll
        for (int rt = 0; rt < 2; ++rt)
            #pragma unroll
            for (int rr = 0; rr < 4; ++rr) {
                const int row = rt * 16 + (lane >> 4) * 4 + rr;
                const int j   = (ctbase + c) * 16 + (lane & 15);
                const float v = fmaxf(acc[c][rt][rr] + b1v[c], 0.f);
                const u16 hb = f2bf(v);
                t_hi[row * SP + j] = hb;
                t_lo[row * SP + j] = f2bf(v - bf2f(hb));
            }
}

__device__ __forceinline__ void acc8(float* a, uint4 q) {
    a[0] += bflo(q.x); a[1] += bfhi(q.x);
    a[2] += bflo(q.y); a[3] += bfhi(q.y);
    a[4] += bflo(q.z); a[5] += bfhi(q.z);
    a[6] += bflo(q.w); a[7] += bfhi(q.w);
}

// ---------------------------------------------------------------------------
// K1: zero cnt || weight repack || x passthrough.
// ---------------------------------------------------------------------------
__global__ __launch_bounds__(256) void zero_repack_x_kernel(
    int* __restrict__ cnt, int N, int ZB,
    const float* __restrict__ W1e, const float* __restrict__ W2e,
    const float* __restrict__ W1n, const float* __restrict__ W2n,
    short* __restrict__ Wb,
    const float* __restrict__ x, float* __restrict__ out_x)
{
    const int RB = 48;
    if (blockIdx.x < (unsigned)ZB) {
        const int i = blockIdx.x * 256 + threadIdx.x;
        if (i < N) cnt[i] = 0;
        return;
    }
    if (blockIdx.x >= (unsigned)(ZB + RB)) {   // x copy
        const int i4 = ((blockIdx.x - ZB - RB) * 256 + threadIdx.x) * 4;
        const int total = N * 3;
        if (i4 + 3 < total) {
            *reinterpret_cast<float4*>(&out_x[i4]) =
                *reinterpret_cast<const float4*>(&x[i4]);
        } else {
            for (int k = i4; k < total && k < i4 + 4; ++k) out_x[k] = x[k];
        }
        return;
    }
    const int gid = (blockIdx.x - ZB) * 256 + threadIdx.x;
    if (gid >= 6 * 8 * 4 * 64) return;
    const int lane = gid & 63;
    int t = gid >> 6;
    const int ks = t & 3; t >>= 2;
    const int ct = t & 7;
    const int m  = t >> 3;
    const float* src;
    switch (m) {
        case 0: src = W1e;             break;
        case 1: src = W1e + 128 * 128; break;
        case 2: src = W2e;             break;
        case 3: src = W1n;             break;
        case 4: src = W1n + 128 * 128; break;
        default: src = W2n;            break;
    }
    const int j  = ct * 16 + (lane & 15);
    const int k0 = ks * 32 + (lane >> 4) * 8;
    bf16x8 hi, lo;
    #pragma unroll
    for (int e = 0; e < 8; ++e) {
        const float w = src[(size_t)(k0 + e) * 128 + j];
        const u16 hb = f2bf(w);
        hi[e] = (short)hb;
        lo[e] = (short)f2bf(w - bf2f(hb));
    }
    short* dst = Wb + (size_t)m * 32768 + (ct * 4 + ks) * 1024 + lane * 8;
    *reinterpret_cast<bf16x8*>(dst)       = hi;
    *reinterpret_cast<bf16x8*>(dst + 512) = lo;   // kept for layout compat (unused)
}

// ---------------------------------------------------------------------------
// K2: node_pre (first PB blocks) || hist (next HB blocks).
// node_pre: 256 thr (4 waves), 32 nodes, hf = bid&1. Coalesced epilogue via
// fp32 LDS staging.
// ---------------------------------------------------------------------------
__global__ __launch_bounds__(256, 8) void pre_hist_kernel(
    const float* __restrict__ h, const short* __restrict__ Wb,
    const float* __restrict__ b1e, const float* __restrict__ b2e,
    const float* __restrict__ Wg,  const float* __restrict__ bg,
    float* __restrict__ R0, u16* __restrict__ Q1b, int N, int PB,
    const int* __restrict__ ei, int E, int* __restrict__ cnt)
{
    __shared__ __align__(16) u16 smem[2 * 32 * SP];
    __shared__ float red_s[4][32];
    u16* ab_hi = smem;
    u16* ab_lo = smem + 32 * SP;

    if (blockIdx.x >= (unsigned)PB) {   // ---- hist path ----
        const int e = (blockIdx.x - PB) * 256 + threadIdx.x;
        if (e < E) atomicAdd(&cnt[ei[E + e]], 1);
        return;
    }

    const int tid  = threadIdx.x, lane = tid & 63, w = tid >> 6;
    const int hf   = blockIdx.x & 1;
    const int base = (blockIdx.x >> 1) * 32;
    const int ctbase = w * NC;

    // stage h -> hi/lo planes
    for (int idx = tid; idx < 32 * 32; idx += 256) {
        const int row = idx >> 5, c4 = (idx & 31) << 2;
        int node = base + row; if (node >= N) node = N - 1;
        const float4 v = *reinterpret_cast<const float4*>(&h[(size_t)node * D + c4]);
        ushort4 hi, lo;
        hi.x = f2bf(v.x); lo.x = f2bf(v.x - bf2f(hi.x));
        hi.y = f2bf(v.y); lo.y = f2bf(v.y - bf2f(hi.y));
        hi.z = f2bf(v.z); lo.z = f2bf(v.z - bf2f(hi.z));
        hi.w = f2bf(v.w); lo.w = f2bf(v.w - bf2f(hi.w));
        *reinterpret_cast<ushort4*>(&ab_hi[row * SP + c4]) = hi;
        *reinterpret_cast<ushort4*>(&ab_lo[row * SP + c4]) = lo;
    }
    __syncthreads();

    float b1v[NC], b2v[NC], wgv[NC];
    #pragma unroll
    for (int c = 0; c < NC; ++c) {
        const int j = (ctbase + c) * 16 + (lane & 15);
        b1v[c] = b1e[j]; b2v[c] = b2e[j]; wgv[c] = Wg[j];
    }
    const float bgv = bg[0];

    f32x4 acc[NC][2];
    #pragma unroll
    for (int c = 0; c < NC; ++c)
        #pragma unroll
        for (int rt = 0; rt < 2; ++rt) acc[c][rt] = (f32x4){0.f, 0.f, 0.f, 0.f};
    layer_mfma(ab_hi, ab_lo, Wb + (size_t)hf * 32768, lane, ctbase, acc);
    __syncthreads();
    store_relu_split(acc, b1v, ab_hi, ab_lo, lane, ctbase);
    __syncthreads();

    f32x4 p[NC][2];
    #pragma unroll
    for (int c = 0; c < NC; ++c)
        #pragma unroll
        for (int rt = 0; rt < 2; ++rt) p[c][rt] = (f32x4){0.f, 0.f, 0.f, 0.f};
    layer_mfma(ab_hi, ab_lo, Wb + (size_t)2 * 32768, lane, ctbase, p);

    // gate partials
    #pragma unroll
    for (int rt = 0; rt < 2; ++rt)
        #pragma unroll
        for (int rr = 0; rr < 4; ++rr) {
            float part = 0.f;
            #pragma unroll
            for (int c = 0; c < NC; ++c) part += (p[c][rt][rr] + b2v[c]) * wgv[c];
            #pragma unroll
            for (int m = 1; m <= 8; m <<= 1) part += __shfl_xor(part, m, 64);
            if ((lane & 15) == 0)
                red_s[w][rt * 16 + (lane >> 4) * 4 + rr] = part;
        }
    __syncthreads();   // red_s ready AND t-plane reads done

    float* fs = reinterpret_cast<float*>(smem);
    #pragma unroll
    for (int rt = 0; rt < 2; ++rt)
        #pragma unroll
        for (int rr = 0; rr < 4; ++rr) {
            const int row = rt * 16 + (lane >> 4) * 4 + rr;
            const float g = sigmoidf(red_s[0][row] + red_s[1][row] +
                                     red_s[2][row] + red_s[3][row] + bgv);
            #pragma unroll
            for (int c = 0; c < NC; ++c) {
                const int j = (ctbase + c) * 16 + (lane & 15);
                fs[row * FS + j] = (p[c][rt][rr] + b2v[c]) * g;
            }
        }
    __syncthreads();

    // coalesced store: thread covers row = tid>>3, cols (tid&7)*16..+15
    const int nl = tid >> 3, cg = tid & 7;
    const int node = base + nl;
    if (node < N) {
        if (hf == 0) {
            #pragma unroll
            for (int k = 0; k < 4; ++k) {
                const float4 v = *reinterpret_cast<const float4*>(&fs[nl * FS + cg * 16 + k * 4]);
                *reinterpret_cast<float4*>(&R0[(size_t)node * D + cg * 16 + k * 4]) = v;
            }
        } else {
            union { u16 s[16]; uint4 v[2]; } pk;
            #pragma unroll
            for (int k = 0; k < 16; ++k) pk.s[k] = f2bf(fs[nl * FS + cg * 16 + k]);
            *reinterpret_cast<uint4*>(&Q1b[(size_t)node * D + cg * 16])     = pk.v[0];
            *reinterpret_cast<uint4*>(&Q1b[(size_t)node * D + cg * 16 + 8]) = pk.v[1];
        }
    }
}

// ---------------------------------------------------------------------------
// K3: single-block scan (N <= 32768)
// ---------------------------------------------------------------------------
__global__ __launch_bounds__(1024) void scan_kernel(
    const int* __restrict__ cnt, int* __restrict__ off, int* __restrict__ cur, int N)
{
    __shared__ int wsum[16];
    const int tid = threadIdx.x, lane = tid & 63, wid = tid >> 6;
    const int IT = (N + 1023) >> 10;
    const int base = tid * IT;
    int v[32];
    int run = 0;
    #pragma unroll
    for (int u = 0; u < 32; ++u) {
        if (u < IT) {
            const int i = base + u;
            run += (i < N) ? cnt[i] : 0;
            v[u] = run;
        }
    }
    const int tot = run;
    int incl = tot;
    #pragma unroll
    for (int o = 1; o < 64; o <<= 1) {
        const int u2 = __shfl_up(incl, o, 64);
        if (lane >= o) incl += u2;
    }
    if (lane == 63) wsum[wid] = incl;
    __syncthreads();
    if (tid < 16) {
        int w = wsum[tid];
        #pragma unroll
        for (int o = 1; o < 16; o <<= 1) {
            const int u2 = __shfl_up(w, o, 16);
            if (tid >= o) w += u2;
        }
        wsum[tid] = w;
    }
    __syncthreads();
    const int tbase = ((wid > 0) ? wsum[wid - 1] : 0) + (incl - tot);
    #pragma unroll
    for (int u = 0; u < 32; ++u) {
        if (u < IT) {
            const int i = base + u;
            if (i < N) {
                const int ex = tbase + ((u > 0) ? v[u - 1] : 0);
                off[i] = ex; cur[i] = ex;
            }
        }
    }
}

// ---------------------------------------------------------------------------
// K4: CSR bucket fill
// ---------------------------------------------------------------------------
__global__ __launch_bounds__(256) void fill_kernel(
    const int* __restrict__ ei, int E, int* __restrict__ cur, int* __restrict__ bucket)
{
    const int e = blockIdx.x * 256 + threadIdx.x;
    if (e < E) {
        const int pos = atomicAdd(&cur[ei[E + e]], 1);
        bucket[pos] = ei[e];
    }
}

// ---------------------------------------------------------------------------
// K5: node MLP + residual, gather fused for r==1.
// grid = 3*ntiles: r = bid%3.  row0: cnt*R0, row1: gathered sum, row2: h.
// ---------------------------------------------------------------------------
__global__ __launch_bounds__(256, 8) void mlp_gather_kernel(
    const float* __restrict__ h,
    const float* __restrict__ R0, const int* __restrict__ cnt,
    const int* __restrict__ off,  const int* __restrict__ bucket,
    const u16* __restrict__ Q1b,  const short* __restrict__ Wb,
    const float* __restrict__ b1n, const float* __restrict__ b2n,
    float* __restrict__ out_h, int N)
{
    __shared__ __align__(16) u16 smem[2 * 32 * SP];
    u16* ab_hi = smem;
    u16* ab_lo = smem + 32 * SP;

    const int tid  = threadIdx.x, lane = tid & 63, w = tid >> 6;
    const int r    = blockIdx.x % 3;
    const int tile = blockIdx.x / 3;
    const int base = tile * 32;
    const int ctbase = w * NC;
    const int nl = tid >> 3, cg = tid & 7;   // 8 threads per node, 16 ch each

    if (r == 1) {
        // ---- fused gather: mi[node] = sum Q1[src] -> hi/lo planes ----
        int node = base + nl; if (node >= N) node = N - 1;
        const int beg = off[node], deg = cnt[node];
        const u16* __restrict__ Qc = Q1b + cg * 16;
        float a[16] = {0.f,0.f,0.f,0.f,0.f,0.f,0.f,0.f,0.f,0.f,0.f,0.f,0.f,0.f,0.f,0.f};
        int i = 0;
        for (; i + 1 < deg; i += 2) {
            const int s0 = bucket[beg + i];
            const int s1 = bucket[beg + i + 1];
            const uint4 qa0 = *reinterpret_cast<const uint4*>(Qc + (size_t)s0 * D);
            const uint4 qb0 = *reinterpret_cast<const uint4*>(Qc + (size_t)s0 * D + 8);
            const uint4 qa1 = *reinterpret_cast<const uint4*>(Qc + (size_t)s1 * D);
            const uint4 qb1 = *reinterpret_cast<const uint4*>(Qc + (size_t)s1 * D + 8);
            acc8(a, qa0); acc8(a + 8, qb0);
            acc8(a, qa1); acc8(a + 8, qb1);
        }
        if (i < deg) {
            const int s = bucket[beg + i];
            const uint4 qa = *reinterpret_cast<const uint4*>(Qc + (size_t)s * D);
            const uint4 qb = *reinterpret_cast<const uint4*>(Qc + (size_t)s * D + 8);
            acc8(a, qa); acc8(a + 8, qb);
        }
        union { u16 s[16]; uint4 v[2]; } ph, pl;
        #pragma unroll
        for (int k = 0; k < 16; ++k) {
            const u16 hb = f2bf(a[k]);
            ph.s[k] = hb;
            pl.s[k] = f2bf(a[k] - bf2f(hb));
        }
        *reinterpret_cast<uint4*>(&ab_hi[nl * SP + cg * 16])     = ph.v[0];
        *reinterpret_cast<uint4*>(&ab_hi[nl * SP + cg * 16 + 8]) = ph.v[1];
        *reinterpret_cast<uint4*>(&ab_lo[nl * SP + cg * 16])     = pl.v[0];
        *reinterpret_cast<uint4*>(&ab_lo[nl * SP + cg * 16 + 8]) = pl.v[1];
    } else {
        const float* __restrict__ src = (r == 0) ? R0 : h;
        for (int idx = tid; idx < 32 * 32; idx += 256) {
            const int row = idx >> 5, c4 = (idx & 31) << 2;
            int node = base + row; if (node >= N) node = N - 1;
            float4 v = *reinterpret_cast<const float4*>(&src[(size_t)node * D + c4]);
            if (r == 0) {
                const float cv = (float)cnt[node];
                v.x *= cv; v.y *= cv; v.z *= cv; v.w *= cv;
            }
            ushort4 hi, lo;
            hi.x = f2bf(v.x); lo.x = f2bf(v.x - bf2f(hi.x));
            hi.y = f2bf(v.y); lo.y = f2bf(v.y - bf2f(hi.y));
            hi.z = f2bf(v.z); lo.z = f2bf(v.z - bf2f(hi.z));
            hi.w = f2bf(v.w); lo.w = f2bf(v.w - bf2f(hi.w));
            *reinterpret_cast<ushort4*>(&ab_hi[row * SP + c4]) = hi;
            *reinterpret_cast<ushort4*>(&ab_lo[row * SP + c4]) = lo;
        }
    }
    __syncthreads();

    float b1v[NC], b2v[NC];
    #pragma unroll
    for (int c = 0; c < NC; ++c) {
        const int j = (ctbase + c) * 16 + (lane & 15);
        b1v[c] = b1n[j]; b2v[c] = b2n[j];
    }

    f32x4 acc[NC][2];
    #pragma unroll
    for (int c = 0; c < NC; ++c)
        #pragma unroll
        for (int rt = 0; rt < 2; ++rt) acc[c][rt] = (f32x4){0.f, 0.f, 0.f, 0.f};
    layer_mfma(ab_hi, ab_lo, Wb + (size_t)((r == 2) ? 4 : 3) * 32768, lane, ctbase, acc);
    __syncthreads();
    store_relu_split(acc, b1v, ab_hi, ab_lo, lane, ctbase);
    __syncthreads();

    f32x4 o[NC][2];
    #pragma unroll
    for (int c = 0; c < NC; ++c)
        #pragma unroll
        for (int rt = 0; rt < 2; ++rt) o[c][rt] = (f32x4){0.f, 0.f, 0.f, 0.f};
    layer_mfma(ab_hi, ab_lo, Wb + (size_t)5 * 32768, lane, ctbase, o);
    __syncthreads();   // t-plane reads complete before fp32 overwrite

    float* fs = reinterpret_cast<float*>(smem);
    #pragma unroll
    for (int c = 0; c < NC; ++c)
        #pragma unroll
        for (int rt = 0; rt < 2; ++rt)
            #pragma unroll
            for (int rr = 0; rr < 4; ++rr) {
                const int row = rt * 16 + (lane >> 4) * 4 + rr;
                const int j   = (ctbase + c) * 16 + (lane & 15);
                fs[row * FS + j] = o[c][rt][rr] + b2v[c];
            }
    __syncthreads();

    // coalesced store with coalesced residual
    const int node = base + nl;
    if (node < N) {
        #pragma unroll
        for (int k = 0; k < 4; ++k) {
            float4 ov = *reinterpret_cast<const float4*>(&fs[nl * FS + cg * 16 + k * 4]);
            const float4 hv = *reinterpret_cast<const float4*>(&h[(size_t)node * D + cg * 16 + k * 4]);
            ov.x += hv.x; ov.y += hv.y; ov.z += hv.z; ov.w += hv.w;
            *reinterpret_cast<float4*>(&out_h[((size_t)node * 3 + r) * D + cg * 16 + k * 4]) = ov;
        }
    }
}

// ---------------------------------------------------------------------------
extern "C" void kernel_launch(void* const* d_in, const int* in_sizes, int n_in,
                              void* d_out, int out_size, void* d_ws, size_t ws_size,
                              hipStream_t stream)
{
    const float* h   = (const float*)d_in[0];
    const float* x   = (const float*)d_in[1];
    const int*   ei  = (const int*)d_in[2];
    const float* W1e = (const float*)d_in[3];
    const float* b1e = (const float*)d_in[4];
    const float* W2e = (const float*)d_in[5];
    const float* b2e = (const float*)d_in[6];
    const float* Wg  = (const float*)d_in[7];
    const float* bg  = (const float*)d_in[8];
    const float* W1n = (const float*)d_in[9];
    const float* b1n = (const float*)d_in[10];
    const float* W2n = (const float*)d_in[11];
    const float* b2n = (const float*)d_in[12];

    const int N = in_sizes[0] / D;
    const int E = in_sizes[2] / 2;

    // workspace: R0 | Q1b(bf16) | Wb | cnt | off | cur | bucket
    float* R0   = (float*)d_ws;
    u16*   Q1b  = (u16*)(R0 + (size_t)N * D);
    short* Wb   = (short*)(Q1b + (size_t)N * D);
    int*   cnt  = (int*)(Wb + 6 * 32768);
    int*   off  = cnt + N;
    int*   cur  = off + N;
    int*   bucket = cur + N;

    float* out_h = (float*)d_out;                 // [N,3,D]
    float* out_x = out_h + (size_t)N * 3 * D;     // [N,3]

    const int ntiles = (N + 31) / 32;
    const int ZB = (N + 255) / 256;               // zero blocks
    const int RB = 48;                            // repack blocks
    const int XB = (N * 3 + 1023) / 1024;         // x-copy blocks (float4)
    const int PB = ntiles * 2;                    // node_pre blocks
    const int HB = (E + 255) / 256;               // hist blocks

    zero_repack_x_kernel<<<ZB + RB + XB, 256, 0, stream>>>(cnt, N, ZB,
                                                           W1e, W2e, W1n, W2n, Wb, x, out_x);
    pre_hist_kernel<<<PB + HB, 256, 0, stream>>>(h, Wb, b1e, b2e, Wg, bg,
                                                 R0, Q1b, N, PB, ei, E, cnt);
    scan_kernel<<<1, 1024, 0, stream>>>(cnt, off, cur, N);
    fill_kernel<<<(E + 255) / 256, 256, 0, stream>>>(ei, E, cur, bucket);
    mlp_gather_kernel<<<ntiles * 3, 256, 0, stream>>>(h, R0, cnt, off, bucket, Q1b, Wb,
                                                      b1n, b2n, out_h, N);
}